// Round 1
// baseline (1419.146 us; speedup 1.0000x reference)
//
#include <hip/hip_runtime.h>
#include <math.h>

// MoBA attention, fp32 baseline (round 0).
// ws layout (floats): q[3.1M] k[3.1M] v[3.1M] attn_out[3.1M] reps[12288]
//                     selmask[49152 u32] rope_tab[131072]  -> ~51.1 MB total.

#define HID   768
#define NH    12
#define DH    64
#define SEQN  2048
#define BATCH 2
#define NTOK  (BATCH*SEQN)   // 4096
#define NB    8
#define BLKSZ 256
#define NEG_INF (-__builtin_huge_valf())

// ---------------------------------------------------------------------------
// RoPE sin/cos table: tab[s*32+f] = (sin, cos) of ang = f32(s) * inv_freq_f32.
// Replicates numpy fp32 sequence: inv_freq = 1.0f / f32(10000^(f/32)).
__global__ __launch_bounds__(256)
void rope_tab_k(float2* __restrict__ tab)
{
    int i = blockIdx.x * 256 + threadIdx.x;
    if (i >= SEQN * 32) return;
    int s = i >> 5, f = i & 31;
    double y  = exp((double)f * (log(10000.0) / 32.0)); // 10000^(f/32), ~exact
    float  yf = (float)y;                                // f32 round (like powf)
    float  invf = 1.0f / yf;                             // f32 divide (like np)
    float  ang  = (float)s * invf;                       // f32 multiply (like np)
    tab[i] = make_float2(sinf(ang), cosf(ang));
}

// ---------------------------------------------------------------------------
// Shared fp32 NT-GEMM tile helpers: C[m,n] = sum_k A[m,k]*W[n,k], K=768.
// Block = 256 threads as 16x16, 4x4 micro-tile, BM=BN=64, BK=16.
__device__ __forceinline__
void tile_load(const float* __restrict__ A, const float* __restrict__ W,
               int m0, int n0, int k0, int lm, int seg,
               float (*As)[68], float (*Bs)[68])
{
    float4 a = *(const float4*)&A[(size_t)(m0 + lm) * HID + k0 + seg * 4];
    float4 b = *(const float4*)&W[(size_t)(n0 + lm) * HID + k0 + seg * 4];
    As[seg*4+0][lm]=a.x; As[seg*4+1][lm]=a.y; As[seg*4+2][lm]=a.z; As[seg*4+3][lm]=a.w;
    Bs[seg*4+0][lm]=b.x; Bs[seg*4+1][lm]=b.y; Bs[seg*4+2][lm]=b.z; Bs[seg*4+3][lm]=b.w;
}

__device__ __forceinline__
void tile_mac(const float (*As)[68], const float (*Bs)[68],
              float acc[4][4], int tx, int ty)
{
    #pragma unroll
    for (int kk = 0; kk < 16; kk++) {
        float4 av = *(const float4*)&As[kk][ty*4];
        float4 bv = *(const float4*)&Bs[kk][tx*4];
        float aa[4] = {av.x, av.y, av.z, av.w};
        float bb[4] = {bv.x, bv.y, bv.z, bv.w};
        #pragma unroll
        for (int i = 0; i < 4; i++)
            #pragma unroll
            for (int j = 0; j < 4; j++)
                acc[i][j] += aa[i] * bb[j];
    }
}

// ---------------------------------------------------------------------------
// QKV projection + fused RoPE epilogue. grid (12 heads, 64 m-tiles, 3 mats).
// Output layout (B,H,S,D). N-tile of 64 == exactly one head.
__global__ __launch_bounds__(256)
void qkv_gemm_k(const float* __restrict__ X,
                const float* __restrict__ Wq, const float* __restrict__ Wk,
                const float* __restrict__ Wv, const float2* __restrict__ tab,
                float* __restrict__ qo, float* __restrict__ ko,
                float* __restrict__ vo)
{
    __shared__ float As[16][68];
    __shared__ float Bs[16][68];
    const int z = blockIdx.z;
    const float* __restrict__ W = (z == 0) ? Wq : (z == 1) ? Wk : Wv;
    float* __restrict__ O = (z == 0) ? qo : (z == 1) ? ko : vo;
    const int n0 = blockIdx.x * 64;
    const int m0 = blockIdx.y * 64;
    const int tid = threadIdx.x;
    const int tx = tid & 15, ty = tid >> 4;
    const int lm = tid >> 2, seg = tid & 3;

    float acc[4][4] = {};
    for (int k0 = 0; k0 < HID; k0 += 16) {
        tile_load(X, W, m0, n0, k0, lm, seg, As, Bs);
        __syncthreads();
        tile_mac(As, Bs, acc, tx, ty);
        __syncthreads();
    }

    const int h = blockIdx.x;
    const int b = m0 >> 11;           // whole 64-token tile in one batch
    #pragma unroll
    for (int i = 0; i < 4; i++) {
        int t = m0 + ty*4 + i;
        int s = t & (SEQN - 1);
        float o4[4];
        if (z < 2) {
            #pragma unroll
            for (int j = 0; j < 4; j++) {
                int d = tx*4 + j;
                float2 sc = tab[(s << 5) + (d & 31)];
                float part = __shfl_xor(acc[i][j], 8);   // lane tx^8 = d +/- 32
                o4[j] = (d < 32) ? (acc[i][j]*sc.y - part*sc.x)
                                 : (acc[i][j]*sc.y + part*sc.x);
            }
        } else {
            #pragma unroll
            for (int j = 0; j < 4; j++) o4[j] = acc[i][j];
        }
        float4 ov = make_float4(o4[0], o4[1], o4[2], o4[3]);
        *(float4*)&O[(((size_t)b*NH + h)*SEQN + s)*DH + tx*4] = ov;
    }
}

// ---------------------------------------------------------------------------
// Block mean of rope'd K. grid = B*H*NB blocks x 64 threads (one per d).
__global__ __launch_bounds__(64)
void block_reps_k(const float* __restrict__ kg, float* __restrict__ reps)
{
    int bhn = blockIdx.x;                       // bh*NB + n
    int d   = threadIdx.x;
    const float* base = kg + (size_t)bhn * BLKSZ * DH;  // == (bh*SEQ + n*256)*64
    double ssum = 0.0;
    for (int j = 0; j < BLKSZ; j++) ssum += (double)base[j*DH + d];
    reps[(size_t)bhn * DH + d] = (float)(ssum * (1.0 / 256.0));
}

// ---------------------------------------------------------------------------
// Top-3 block selection per (b,h,q), fp64 scores, tie-break = lowest index.
// Replicates ref: future blocks -> -inf (still selectable!), cur -> +max.
__global__ __launch_bounds__(256)
void select_topk_k(const float* __restrict__ qg, const float* __restrict__ reps,
                   unsigned* __restrict__ selm)
{
    __shared__ float rs[NB][DH];
    const int bh = blockIdx.x;
    const int tid = threadIdx.x;
    for (int idx = tid; idx < NB*DH; idx += 256)
        rs[idx >> 6][idx & 63] = reps[(size_t)bh*NB*DH + idx];
    __syncthreads();

    for (int qq = tid; qq < SEQN; qq += 256) {
        const float* qv = &qg[((size_t)bh*SEQN + qq)*DH];
        float qr[DH];
        #pragma unroll
        for (int c = 0; c < 16; c++) {
            float4 t = *(const float4*)&qv[c*4];
            qr[c*4+0]=t.x; qr[c*4+1]=t.y; qr[c*4+2]=t.z; qr[c*4+3]=t.w;
        }
        const int cur = qq >> 8;
        double sc[NB];
        #pragma unroll
        for (int n = 0; n < NB; n++) {
            double ssum = 0.0;
            for (int d = 0; d < DH; d++) ssum += (double)qr[d] * (double)rs[n][d];
            sc[n] = ssum * 0.125;
        }
        for (int n = cur + 1; n < NB; n++) sc[n] = -1e300;  // future
        sc[cur] = 1e300;                                     // forced pick
        unsigned mask = 0;
        for (int p = 0; p < 3; p++) {
            int bi = -1; double bv = 0.0;
            for (int n = 0; n < NB; n++) {
                if ((mask >> n) & 1) continue;
                if (bi < 0 || sc[n] > bv) { bi = n; bv = sc[n]; }
            }
            mask |= 1u << bi;
        }
        selm[(size_t)bh*SEQN + qq] = mask;
    }
}

// ---------------------------------------------------------------------------
// Flash-style attention over selected blocks. Block = 256 thr = one (bh,
// 64-query tile). Skips key blocks nobody in the tile selected.
// Thread (ty,tx): scores for 4q x 2k; PV accum for 4q x 4d.
__global__ __launch_bounds__(256)
void moba_attn_k(const float* __restrict__ qg, const float* __restrict__ kg,
                 const float* __restrict__ vg, const unsigned* __restrict__ selm,
                 float* __restrict__ ao)
{
    __shared__ float qs[64][66];
    __shared__ float ks[32][66];
    __shared__ float vs[32][64];
    __shared__ float ps[64][34];
    __shared__ unsigned smArr[64];
    __shared__ unsigned sunion;

    const int bh = blockIdx.y;
    const int q0 = blockIdx.x * 64;
    const int cur = q0 >> 8;
    const int tid = threadIdx.x;
    const int tx = tid & 15, ty = tid >> 4;
    const size_t bhS = (size_t)bh * SEQN;

    #pragma unroll
    for (int r = 0; r < 4; r++) {
        int fi = r*256 + tid, qq = fi >> 4, c = fi & 15;
        float4 t = *(const float4*)&qg[(bhS + q0 + qq)*DH + c*4];
        qs[qq][c*4+0]=t.x; qs[qq][c*4+1]=t.y; qs[qq][c*4+2]=t.z; qs[qq][c*4+3]=t.w;
    }
    if (tid == 0) sunion = 0;
    __syncthreads();
    if (tid < 64) {
        unsigned mk = selm[bhS + q0 + tid];
        smArr[tid] = mk;
        atomicOr(&sunion, mk);
    }
    __syncthreads();
    const unsigned uni = sunion;
    unsigned msk[4];
    #pragma unroll
    for (int i = 0; i < 4; i++) msk[i] = smArr[ty*4 + i];

    float m_i[4], l_i[4], o[4][4];
    #pragma unroll
    for (int i = 0; i < 4; i++) {
        m_i[i] = NEG_INF; l_i[i] = 0.f;
        #pragma unroll
        for (int j = 0; j < 4; j++) o[i][j] = 0.f;
    }

    for (int n = 0; n < NB; n++) {
        if (!((uni >> n) & 1)) continue;
        const bool iscur = (n == cur);
        for (int c2 = 0; c2 < BLKSZ; c2 += 32) {
            const int kbase = n*BLKSZ + c2;
            #pragma unroll
            for (int r = 0; r < 2; r++) {
                int fi = r*256 + tid, ky = fi >> 4, c = fi & 15;
                float4 kv = *(const float4*)&kg[(bhS + kbase + ky)*DH + c*4];
                ks[ky][c*4+0]=kv.x; ks[ky][c*4+1]=kv.y;
                ks[ky][c*4+2]=kv.z; ks[ky][c*4+3]=kv.w;
                float4 vv = *(const float4*)&vg[(bhS + kbase + ky)*DH + c*4];
                *(float4*)&vs[ky][c*4] = vv;
            }
            __syncthreads();

            // ---- scores: 4q x 2k dot products over d (float2 LDS reads)
            float sacc[4][2] = {};
            const float2* q2[4];
            #pragma unroll
            for (int i = 0; i < 4; i++) q2[i] = (const float2*)&qs[ty*4+i][0];
            const float2* k2a = (const float2*)&ks[tx*2+0][0];
            const float2* k2b = (const float2*)&ks[tx*2+1][0];
            #pragma unroll
            for (int dd = 0; dd < 32; dd++) {
                float2 ka = k2a[dd], kb = k2b[dd];
                #pragma unroll
                for (int i = 0; i < 4; i++) {
                    float2 qa = q2[i][dd];
                    sacc[i][0] += qa.x*ka.x + qa.y*ka.y;
                    sacc[i][1] += qa.x*kb.x + qa.y*kb.y;
                }
            }

            // ---- mask + online softmax (row = 16 lanes sharing ty)
            #pragma unroll
            for (int i = 0; i < 4; i++) {
                const int qpos = q0 + ty*4 + i;
                const bool bsel = (msk[i] >> n) & 1;
                const int kp0 = kbase + tx*2;
                float f0 = (bsel && (!iscur || kp0     <= qpos)) ? sacc[i][0]*0.125f : NEG_INF;
                float f1 = (bsel && (!iscur || kp0 + 1 <= qpos)) ? sacc[i][1]*0.125f : NEG_INF;
                float rm = fmaxf(f0, f1);
                #pragma unroll
                for (int off = 8; off >= 1; off >>= 1)
                    rm = fmaxf(rm, __shfl_xor(rm, off, 16));
                const float mnew  = fmaxf(m_i[i], rm);
                const float alpha = (mnew == NEG_INF) ? 1.f : __expf(m_i[i] - mnew);
                const float p0 = (f0 == NEG_INF) ? 0.f : __expf(f0 - mnew);
                const float p1 = (f1 == NEG_INF) ? 0.f : __expf(f1 - mnew);
                float rsum = p0 + p1;
                #pragma unroll
                for (int off = 8; off >= 1; off >>= 1)
                    rsum += __shfl_xor(rsum, off, 16);
                l_i[i] = l_i[i]*alpha + rsum;
                m_i[i] = mnew;
                o[i][0]*=alpha; o[i][1]*=alpha; o[i][2]*=alpha; o[i][3]*=alpha;
                ps[ty*4+i][tx*2+0] = p0;
                ps[ty*4+i][tx*2+1] = p1;
            }
            __syncthreads();

            // ---- PV: o[4q][4d] += P(4q x 32k) * V(32k x 4d)
            #pragma unroll 8
            for (int kk2 = 0; kk2 < 32; kk2++) {
                float4 vv = *(const float4*)&vs[kk2][tx*4];
                #pragma unroll
                for (int i = 0; i < 4; i++) {
                    float pp = ps[ty*4+i][kk2];
                    o[i][0] += pp*vv.x; o[i][1] += pp*vv.y;
                    o[i][2] += pp*vv.z; o[i][3] += pp*vv.w;
                }
            }
            __syncthreads();
        }
    }

    const int b = bh / NH, h = bh % NH;
    #pragma unroll
    for (int i = 0; i < 4; i++) {
        float inv = 1.0f / l_i[i];
        float4 ov = make_float4(o[i][0]*inv, o[i][1]*inv, o[i][2]*inv, o[i][3]*inv);
        *(float4*)&ao[((size_t)b*SEQN + q0 + ty*4 + i)*HID + h*DH + tx*4] = ov;
    }
}

// ---------------------------------------------------------------------------
// Output projection: d_out = attn_out(4096x768) @ Wo^T.
__global__ __launch_bounds__(256)
void out_gemm_k(const float* __restrict__ A, const float* __restrict__ W,
                float* __restrict__ C)
{
    __shared__ float As[16][68];
    __shared__ float Bs[16][68];
    const int n0 = blockIdx.x * 64;
    const int m0 = blockIdx.y * 64;
    const int tid = threadIdx.x;
    const int tx = tid & 15, ty = tid >> 4;
    const int lm = tid >> 2, seg = tid & 3;

    float acc[4][4] = {};
    for (int k0 = 0; k0 < HID; k0 += 16) {
        tile_load(A, W, m0, n0, k0, lm, seg, As, Bs);
        __syncthreads();
        tile_mac(As, Bs, acc, tx, ty);
        __syncthreads();
    }
    #pragma unroll
    for (int i = 0; i < 4; i++) {
        float4 ov = make_float4(acc[i][0], acc[i][1], acc[i][2], acc[i][3]);
        *(float4*)&C[(size_t)(m0 + ty*4 + i)*HID + n0 + tx*4] = ov;
    }
}

// ---------------------------------------------------------------------------
extern "C" void kernel_launch(void* const* d_in, const int* in_sizes, int n_in,
                              void* d_out, int out_size, void* d_ws, size_t ws_size,
                              hipStream_t stream)
{
    const float* X  = (const float*)d_in[0];
    const float* Wq = (const float*)d_in[1];
    const float* Wk = (const float*)d_in[2];
    const float* Wv = (const float*)d_in[3];
    const float* Wo = (const float*)d_in[4];
    float* out = (float*)d_out;

    float* q_ws = (float*)d_ws;
    float* k_ws = q_ws + (size_t)NTOK*HID;
    float* v_ws = k_ws + (size_t)NTOK*HID;
    float* ao   = v_ws + (size_t)NTOK*HID;
    float* reps = ao   + (size_t)NTOK*HID;
    unsigned* selm = (unsigned*)(reps + (size_t)BATCH*NH*NB*DH);
    float2* tab = (float2*)(selm + (size_t)BATCH*NH*SEQN);

    rope_tab_k  <<<dim3((SEQN*32 + 255)/256), 256, 0, stream>>>(tab);
    qkv_gemm_k  <<<dim3(HID/64, NTOK/64, 3),  256, 0, stream>>>(X, Wq, Wk, Wv, tab,
                                                                q_ws, k_ws, v_ws);
    block_reps_k<<<dim3(BATCH*NH*NB),          64, 0, stream>>>(k_ws, reps);
    select_topk_k<<<dim3(BATCH*NH),           256, 0, stream>>>(q_ws, reps, selm);
    moba_attn_k <<<dim3(SEQN/64, BATCH*NH),   256, 0, stream>>>(q_ws, k_ws, v_ws,
                                                                selm, ao);
    out_gemm_k  <<<dim3(HID/64, NTOK/64),     256, 0, stream>>>(ao, Wo, out);
}

// Round 2
// 814.532 us; speedup vs baseline: 1.7423x; 1.7423x over previous
//
#include <hip/hip_runtime.h>
#include <math.h>

// MoBA attention, round 1: split-bf16 MFMA flash attention.
// Selection path (fp32 q/k + fp64 scores) untouched for top-k fidelity.

#define HID   768
#define NH    12
#define DH    64
#define SEQN  2048
#define BATCH 2
#define NTOK  (BATCH*SEQN)   // 4096
#define NB    8
#define BLKSZ 256
#define NEG_INF (-__builtin_huge_valf())

typedef __bf16 v8bf __attribute__((ext_vector_type(8)));
typedef float  v4f  __attribute__((ext_vector_type(4)));

__device__ __forceinline__ unsigned short f2bf(float f) {
    unsigned u = __builtin_bit_cast(unsigned, f);
    u = (u + 0x7fffu + ((u >> 16) & 1u)) >> 16;      // RNE
    return (unsigned short)u;
}
__device__ __forceinline__ float bf2f(unsigned short h) {
    unsigned u = ((unsigned)h) << 16;
    return __builtin_bit_cast(float, u);
}

// ---------------------------------------------------------------------------
// RoPE sin/cos table, replicating numpy fp32 op sequence.
__global__ __launch_bounds__(256)
void rope_tab_k(float2* __restrict__ tab)
{
    int i = blockIdx.x * 256 + threadIdx.x;
    if (i >= SEQN * 32) return;
    int s = i >> 5, f = i & 31;
    double y  = exp((double)f * (log(10000.0) / 32.0));
    float  yf = (float)y;
    float  invf = 1.0f / yf;
    float  ang  = (float)s * invf;
    tab[i] = make_float2(sinf(ang), cosf(ang));
}

// ---------------------------------------------------------------------------
// fp32 NT-GEMM tile helpers (kept for QKV / output projections this round).
__device__ __forceinline__
void tile_load(const float* __restrict__ A, const float* __restrict__ W,
               int m0, int n0, int k0, int lm, int seg,
               float (*As)[68], float (*Bs)[68])
{
    float4 a = *(const float4*)&A[(size_t)(m0 + lm) * HID + k0 + seg * 4];
    float4 b = *(const float4*)&W[(size_t)(n0 + lm) * HID + k0 + seg * 4];
    As[seg*4+0][lm]=a.x; As[seg*4+1][lm]=a.y; As[seg*4+2][lm]=a.z; As[seg*4+3][lm]=a.w;
    Bs[seg*4+0][lm]=b.x; Bs[seg*4+1][lm]=b.y; Bs[seg*4+2][lm]=b.z; Bs[seg*4+3][lm]=b.w;
}

__device__ __forceinline__
void tile_mac(const float (*As)[68], const float (*Bs)[68],
              float acc[4][4], int tx, int ty)
{
    #pragma unroll
    for (int kk = 0; kk < 16; kk++) {
        float4 av = *(const float4*)&As[kk][ty*4];
        float4 bv = *(const float4*)&Bs[kk][tx*4];
        float aa[4] = {av.x, av.y, av.z, av.w};
        float bb[4] = {bv.x, bv.y, bv.z, bv.w};
        #pragma unroll
        for (int i = 0; i < 4; i++)
            #pragma unroll
            for (int j = 0; j < 4; j++)
                acc[i][j] += aa[i] * bb[j];
    }
}

// ---------------------------------------------------------------------------
// QKV projection + RoPE. Emits fp32 q,k (for selection) and split-bf16
// q,k (row-major d) and v^T (d-major) for the MFMA attention kernel.
__global__ __launch_bounds__(256)
void qkv_gemm_k(const float* __restrict__ X,
                const float* __restrict__ Wq, const float* __restrict__ Wk,
                const float* __restrict__ Wv, const float2* __restrict__ tab,
                float* __restrict__ qo, float* __restrict__ ko,
                unsigned short* __restrict__ qhi, unsigned short* __restrict__ qlo,
                unsigned short* __restrict__ khi, unsigned short* __restrict__ klo,
                unsigned short* __restrict__ vthi, unsigned short* __restrict__ vtlo)
{
    __shared__ float As[16][68];
    __shared__ float Bs[16][68];
    const int z = blockIdx.z;
    const float* __restrict__ W = (z == 0) ? Wq : (z == 1) ? Wk : Wv;
    const int n0 = blockIdx.x * 64;
    const int m0 = blockIdx.y * 64;
    const int tid = threadIdx.x;
    const int tx = tid & 15, ty = tid >> 4;
    const int lm = tid >> 2, seg = tid & 3;

    float acc[4][4] = {};
    for (int k0 = 0; k0 < HID; k0 += 16) {
        tile_load(X, W, m0, n0, k0, lm, seg, As, Bs);
        __syncthreads();
        tile_mac(As, Bs, acc, tx, ty);
        __syncthreads();
    }

    const int h = blockIdx.x;
    const int b = m0 >> 11;
    #pragma unroll
    for (int i = 0; i < 4; i++) {
        int t = m0 + ty*4 + i;
        int s = t & (SEQN - 1);
        if (z < 2) {
            float o4[4];
            #pragma unroll
            for (int j = 0; j < 4; j++) {
                int d = tx*4 + j;
                float2 sc = tab[(s << 5) + (d & 31)];
                float part = __shfl_xor(acc[i][j], 8);
                o4[j] = (d < 32) ? (acc[i][j]*sc.y - part*sc.x)
                                 : (acc[i][j]*sc.y + part*sc.x);
            }
            size_t base = (((size_t)b*NH + h)*SEQN + s)*DH + tx*4;
            float* O = (z == 0) ? qo : ko;
            *(float4*)&O[base] = make_float4(o4[0], o4[1], o4[2], o4[3]);
            unsigned short h4[4], l4[4];
            #pragma unroll
            for (int j = 0; j < 4; j++) {
                h4[j] = f2bf(o4[j]);
                l4[j] = f2bf(o4[j] - bf2f(h4[j]));
            }
            unsigned short* Hx = (z == 0) ? qhi : khi;
            unsigned short* Lx = (z == 0) ? qlo : klo;
            *(ushort4*)&Hx[base] = make_ushort4(h4[0], h4[1], h4[2], h4[3]);
            *(ushort4*)&Lx[base] = make_ushort4(l4[0], l4[1], l4[2], l4[3]);
        } else {
            #pragma unroll
            for (int j = 0; j < 4; j++) {
                int d = tx*4 + j;
                float val = acc[i][j];
                size_t tb = (((size_t)b*NH + h)*DH + d)*SEQN + s;
                unsigned short hh = f2bf(val);
                vthi[tb] = hh;
                vtlo[tb] = f2bf(val - bf2f(hh));
            }
        }
    }
}

// ---------------------------------------------------------------------------
// Block mean of rope'd K (fp32), fp64 accumulation.
__global__ __launch_bounds__(64)
void block_reps_k(const float* __restrict__ kg, float* __restrict__ reps)
{
    int bhn = blockIdx.x;
    int d   = threadIdx.x;
    const float* base = kg + (size_t)bhn * BLKSZ * DH;
    double ssum = 0.0;
    for (int j = 0; j < BLKSZ; j++) ssum += (double)base[j*DH + d];
    reps[(size_t)bhn * DH + d] = (float)(ssum * (1.0 / 256.0));
}

// ---------------------------------------------------------------------------
// Top-3 block selection, fp64 scores, tie-break lowest index (jax semantics).
__global__ __launch_bounds__(256)
void select_topk_k(const float* __restrict__ qg, const float* __restrict__ reps,
                   unsigned* __restrict__ selm)
{
    __shared__ float rs[NB][DH];
    const int bh = blockIdx.x;
    const int tid = threadIdx.x;
    for (int idx = tid; idx < NB*DH; idx += 256)
        rs[idx >> 6][idx & 63] = reps[(size_t)bh*NB*DH + idx];
    __syncthreads();

    for (int qq = tid; qq < SEQN; qq += 256) {
        const float* qv = &qg[((size_t)bh*SEQN + qq)*DH];
        float qr[DH];
        #pragma unroll
        for (int c = 0; c < 16; c++) {
            float4 t = *(const float4*)&qv[c*4];
            qr[c*4+0]=t.x; qr[c*4+1]=t.y; qr[c*4+2]=t.z; qr[c*4+3]=t.w;
        }
        const int cur = qq >> 8;
        double sc[NB];
        #pragma unroll
        for (int n = 0; n < NB; n++) {
            double ssum = 0.0;
            for (int d = 0; d < DH; d++) ssum += (double)qr[d] * (double)rs[n][d];
            sc[n] = ssum * 0.125;
        }
        for (int n = cur + 1; n < NB; n++) sc[n] = -1e300;
        sc[cur] = 1e300;
        unsigned mask = 0;
        for (int p = 0; p < 3; p++) {
            int bi = -1; double bv = 0.0;
            for (int n = 0; n < NB; n++) {
                if ((mask >> n) & 1) continue;
                if (bi < 0 || sc[n] > bv) { bi = n; bv = sc[n]; }
            }
            mask |= 1u << bi;
        }
        selm[(size_t)bh*SEQN + qq] = mask;
    }
}

// ---------------------------------------------------------------------------
// Split-bf16 MFMA flash attention.
// Block = 256 thr = 4 waves = one (bh, 64-query tile). Wave w owns 16
// queries (cols). S computed transposed (M=keys,N=queries) so softmax state
// is per-lane. P round-trips LDS (C-layout -> A-layout). No barriers in the
// divergent block loop (per-wave union skipping).
__global__ __launch_bounds__(256)
void moba_attn_mfma(const unsigned short* __restrict__ qhi,
                    const unsigned short* __restrict__ qlo,
                    const unsigned short* __restrict__ khi,
                    const unsigned short* __restrict__ klo,
                    const unsigned short* __restrict__ vthi,
                    const unsigned short* __restrict__ vtlo,
                    const unsigned* __restrict__ selm,
                    float* __restrict__ ao)
{
    __shared__ unsigned smArr[64];
    __shared__ unsigned short plds[4][2][16][72];  // [wave][hi/lo][q][key+pad]

    const int bh  = blockIdx.y;
    const int q0  = blockIdx.x * 64;
    const int cur = q0 >> 8;
    const int tid = threadIdx.x;
    const int wave = tid >> 6;
    const int lane = tid & 63;
    const int col  = lane & 15;        // query within wave / MFMA n or m
    const int quad = lane >> 4;
    const int qw0  = q0 + wave * 16;
    const size_t bhS = (size_t)bh * SEQN;

    if (tid < 64) smArr[tid] = selm[bhS + q0 + tid];
    __syncthreads();
    const unsigned mymask = smArr[wave*16 + col];
    unsigned uni = mymask;
    #pragma unroll
    for (int off = 1; off < 16; off <<= 1) uni |= __shfl_xor(uni, off, 16);

    // Q B-fragments (B[k=d][n=q] = Q[q][d], 8 contiguous bf16 per lane)
    const size_t qbase = (bhS + qw0 + col) * DH + quad * 8;
    v8bf qh[2], ql[2];
    #pragma unroll
    for (int ks = 0; ks < 2; ks++) {
        qh[ks] = *reinterpret_cast<const v8bf*>(&qhi[qbase + ks*32]);
        ql[ks] = *reinterpret_cast<const v8bf*>(&qlo[qbase + ks*32]);
    }

    const v4f zero4 = {0.f, 0.f, 0.f, 0.f};
    v4f oacc[4] = {zero4, zero4, zero4, zero4};
    float m_i = NEG_INF, l_i = 0.f;
    const int qpos = qw0 + col;

    for (int n = 0; n < NB; n++) {
        if (!((uni >> n) & 1)) continue;
        const bool iscur = (n == cur);
        const bool selq  = (mymask >> n) & 1;
        for (int c2 = 0; c2 < 4; c2++) {
            const int kb = n * BLKSZ + c2 * 64;

            // ---- S^T[64k x 16q] via 3-term split-bf16 MFMA
            v4f sf[4];
            #pragma unroll
            for (int mt = 0; mt < 4; mt++) {
                const size_t kbase = (bhS + kb + mt*16 + col) * DH + quad * 8;
                v8bf ah0 = *reinterpret_cast<const v8bf*>(&khi[kbase]);
                v8bf ah1 = *reinterpret_cast<const v8bf*>(&khi[kbase + 32]);
                v8bf al0 = *reinterpret_cast<const v8bf*>(&klo[kbase]);
                v8bf al1 = *reinterpret_cast<const v8bf*>(&klo[kbase + 32]);
                v4f c = zero4;
                c = __builtin_amdgcn_mfma_f32_16x16x32_bf16(ah0, qh[0], c, 0, 0, 0);
                c = __builtin_amdgcn_mfma_f32_16x16x32_bf16(ah1, qh[1], c, 0, 0, 0);
                c = __builtin_amdgcn_mfma_f32_16x16x32_bf16(ah0, ql[0], c, 0, 0, 0);
                c = __builtin_amdgcn_mfma_f32_16x16x32_bf16(ah1, ql[1], c, 0, 0, 0);
                c = __builtin_amdgcn_mfma_f32_16x16x32_bf16(al0, qh[0], c, 0, 0, 0);
                c = __builtin_amdgcn_mfma_f32_16x16x32_bf16(al1, qh[1], c, 0, 0, 0);
                sf[mt] = c;
            }

            // ---- mask + scale; row max (per query = per lane col)
            float rm = NEG_INF;
            #pragma unroll
            for (int mt = 0; mt < 4; mt++)
                #pragma unroll
                for (int r = 0; r < 4; r++) {
                    const int kidx = kb + mt*16 + quad*4 + r;
                    const bool ok = selq && (!iscur || kidx <= qpos);
                    float f = ok ? sf[mt][r] * 0.125f : NEG_INF;
                    sf[mt][r] = f;
                    rm = fmaxf(rm, f);
                }
            rm = fmaxf(rm, __shfl_xor(rm, 16));
            rm = fmaxf(rm, __shfl_xor(rm, 32));
            const float mnew  = fmaxf(m_i, rm);
            const float alpha = (m_i == NEG_INF) ? 0.f : __expf(m_i - mnew);
            const float mex   = (mnew == NEG_INF) ? 0.f : mnew;

            // ---- exp, split-bf16 P into LDS (A-layout rows = query)
            float lsum = 0.f;
            #pragma unroll
            for (int mt = 0; mt < 4; mt++)
                #pragma unroll
                for (int r = 0; r < 4; r++) {
                    float p = __expf(sf[mt][r] - mex);  // exp(-inf)=0 for masked
                    lsum += p;
                    unsigned short ph = f2bf(p);
                    plds[wave][0][col][mt*16 + quad*4 + r] = ph;
                    plds[wave][1][col][mt*16 + quad*4 + r] = f2bf(p - bf2f(ph));
                }
            lsum += __shfl_xor(lsum, 16);
            lsum += __shfl_xor(lsum, 32);
            l_i = l_i * alpha + lsum;
            m_i = mnew;

            // ---- rescale O rows (row = query quad*4+r; alpha lives at col)
            float ar[4];
            #pragma unroll
            for (int r = 0; r < 4; r++) ar[r] = __shfl(alpha, quad*4 + r, 16);
            #pragma unroll
            for (int nt = 0; nt < 4; nt++)
                #pragma unroll
                for (int r = 0; r < 4; r++) oacc[nt][r] *= ar[r];

            __threadfence_block();   // wave-local LDS visibility (no barrier)

            // ---- O[16q x 64d] += P * V  (3-term split)
            #pragma unroll
            for (int ks2 = 0; ks2 < 2; ks2++) {
                v8bf ph = *reinterpret_cast<const v8bf*>(&plds[wave][0][col][ks2*32 + quad*8]);
                v8bf pl = *reinterpret_cast<const v8bf*>(&plds[wave][1][col][ks2*32 + quad*8]);
                #pragma unroll
                for (int nt = 0; nt < 4; nt++) {
                    const size_t vb = ((size_t)bh*DH + nt*16 + col) * SEQN
                                    + kb + ks2*32 + quad*8;
                    v8bf vh = *reinterpret_cast<const v8bf*>(&vthi[vb]);
                    v8bf vl = *reinterpret_cast<const v8bf*>(&vtlo[vb]);
                    oacc[nt] = __builtin_amdgcn_mfma_f32_16x16x32_bf16(ph, vh, oacc[nt], 0, 0, 0);
                    oacc[nt] = __builtin_amdgcn_mfma_f32_16x16x32_bf16(pl, vh, oacc[nt], 0, 0, 0);
                    oacc[nt] = __builtin_amdgcn_mfma_f32_16x16x32_bf16(ph, vl, oacc[nt], 0, 0, 0);
                }
            }
        }
    }

    // ---- epilogue: normalize rows, store (B,S,H*D) fp32
    const int b = bh / NH, h = bh % NH;
    const float invl = 1.f / l_i;
    float ir[4];
    #pragma unroll
    for (int r = 0; r < 4; r++) ir[r] = __shfl(invl, quad*4 + r, 16);
    #pragma unroll
    for (int nt = 0; nt < 4; nt++)
        #pragma unroll
        for (int r = 0; r < 4; r++) {
            const int qi = qw0 + quad*4 + r;
            ao[((size_t)b*SEQN + qi)*HID + h*DH + nt*16 + col] = oacc[nt][r] * ir[r];
        }
}

// ---------------------------------------------------------------------------
// Output projection: d_out = attn_out(4096x768) @ Wo^T (fp32).
__global__ __launch_bounds__(256)
void out_gemm_k(const float* __restrict__ A, const float* __restrict__ W,
                float* __restrict__ C)
{
    __shared__ float As[16][68];
    __shared__ float Bs[16][68];
    const int n0 = blockIdx.x * 64;
    const int m0 = blockIdx.y * 64;
    const int tid = threadIdx.x;
    const int tx = tid & 15, ty = tid >> 4;
    const int lm = tid >> 2, seg = tid & 3;

    float acc[4][4] = {};
    for (int k0 = 0; k0 < HID; k0 += 16) {
        tile_load(A, W, m0, n0, k0, lm, seg, As, Bs);
        __syncthreads();
        tile_mac(As, Bs, acc, tx, ty);
        __syncthreads();
    }
    #pragma unroll
    for (int i = 0; i < 4; i++) {
        float4 ov = make_float4(acc[i][0], acc[i][1], acc[i][2], acc[i][3]);
        *(float4*)&C[(size_t)(m0 + ty*4 + i)*HID + n0 + tx*4] = ov;
    }
}

// ---------------------------------------------------------------------------
extern "C" void kernel_launch(void* const* d_in, const int* in_sizes, int n_in,
                              void* d_out, int out_size, void* d_ws, size_t ws_size,
                              hipStream_t stream)
{
    const float* X  = (const float*)d_in[0];
    const float* Wq = (const float*)d_in[1];
    const float* Wk = (const float*)d_in[2];
    const float* Wv = (const float*)d_in[3];
    const float* Wo = (const float*)d_in[4];
    float* out = (float*)d_out;

    // fp32 region
    float* q_ws = (float*)d_ws;                       // 3,145,728 f
    float* k_ws = q_ws + (size_t)NTOK*HID;            // 3,145,728 f
    float* ao   = k_ws;                               // ALIAS: k_ws dead after reps
    float* reps = k_ws + (size_t)NTOK*HID;            // 12,288 f
    unsigned* selm = (unsigned*)(reps + (size_t)BATCH*NH*NB*DH);   // 49,152 u32
    float2* tab = (float2*)(selm + (size_t)BATCH*NH*SEQN);         // 65,536 f2
    // bf16 region
    unsigned short* qhi  = (unsigned short*)(tab + SEQN*32);
    unsigned short* qlo  = qhi  + (size_t)NTOK*HID;
    unsigned short* khi  = qlo  + (size_t)NTOK*HID;
    unsigned short* klo  = khi  + (size_t)NTOK*HID;
    unsigned short* vthi = klo  + (size_t)NTOK*HID;
    unsigned short* vtlo = vthi + (size_t)NTOK*HID;

    rope_tab_k  <<<dim3((SEQN*32 + 255)/256), 256, 0, stream>>>(tab);
    qkv_gemm_k  <<<dim3(HID/64, NTOK/64, 3),  256, 0, stream>>>(
                    X, Wq, Wk, Wv, tab, q_ws, k_ws,
                    qhi, qlo, khi, klo, vthi, vtlo);
    block_reps_k<<<dim3(BATCH*NH*NB),          64, 0, stream>>>(k_ws, reps);
    select_topk_k<<<dim3(BATCH*NH),           256, 0, stream>>>(q_ws, reps, selm);
    moba_attn_mfma<<<dim3(SEQN/64, BATCH*NH), 256, 0, stream>>>(
                    qhi, qlo, khi, klo, vthi, vtlo, selm, ao);
    out_gemm_k  <<<dim3(HID/64, NTOK/64),     256, 0, stream>>>(ao, Wo, out);
}

// Round 3
// 704.118 us; speedup vs baseline: 2.0155x; 1.1568x over previous
//
#include <hip/hip_runtime.h>
#include <math.h>

// MoBA attention, round 2: MFMA split-bf16 everywhere.
// - QKV GEMM: 6-product 3-way-bf16 split (fp32-grade) + fused RoPE epilogue.
// - Selection: fp32 q + fp64-reduced block reps (deterministic) -> same flip
//   risk as the round-0/1 proven path.
// - Attention: per-wave flash tiles, 128-thr wgs, XCD-local bh mapping,
//   S = 3-product split, PV = (Ph+Pl)*Vh.
// - Out-proj: 3-product split GEMM.

#define HID   768
#define NH    12
#define DH    64
#define SEQN  2048
#define BATCH 2
#define NTOK  (BATCH*SEQN)   // 4096
#define NB    8
#define BLKSZ 256
#define NEG_INF (-__builtin_huge_valf())

typedef __bf16 v8bf __attribute__((ext_vector_type(8)));
typedef unsigned short v8us __attribute__((ext_vector_type(8)));
typedef float  v4f  __attribute__((ext_vector_type(4)));

union BF8 { v8us u; v8bf b; };

__device__ __forceinline__ unsigned short f2bf(float f) {
    unsigned u = __builtin_bit_cast(unsigned, f);
    u = (u + 0x7fffu + ((u >> 16) & 1u)) >> 16;      // RNE
    return (unsigned short)u;
}
__device__ __forceinline__ float bf2f(unsigned short h) {
    unsigned u = ((unsigned)h) << 16;
    return __builtin_bit_cast(float, u);
}
__device__ __forceinline__ v8bf ldbf8(const unsigned short* p) {
    return *reinterpret_cast<const v8bf*>(p);
}

// ---------------------------------------------------------------------------
// RoPE table: fp32 angle (numpy op order), fp64 trig, round to fp32.
__global__ __launch_bounds__(256)
void rope_tab_k(float2* __restrict__ tab)
{
    int i = blockIdx.x * 256 + threadIdx.x;
    if (i >= SEQN * 32) return;
    int s = i >> 5, f = i & 31;
    double y  = exp((double)f * (log(10000.0) / 32.0));
    float  yf = (float)y;
    float  invf = 1.0f / yf;
    float  ang  = (float)s * invf;
    tab[i] = make_float2((float)sin((double)ang), (float)cos((double)ang));
}

// ---------------------------------------------------------------------------
// fp32 -> 3-way / 2-way bf16 splits.
__global__ __launch_bounds__(256)
void split3_k(const float* __restrict__ src, int n,
              unsigned short* __restrict__ oh, unsigned short* __restrict__ om,
              unsigned short* __restrict__ ol)
{
    int i = blockIdx.x * 256 + threadIdx.x;
    if (i >= n) return;
    float x = src[i];
    unsigned short h = f2bf(x);
    float r1 = x - bf2f(h);
    unsigned short m = f2bf(r1);
    float r2 = r1 - bf2f(m);
    oh[i] = h; om[i] = m; ol[i] = f2bf(r2);
}

__global__ __launch_bounds__(256)
void split2_k(const float* __restrict__ src, int n,
              unsigned short* __restrict__ oh, unsigned short* __restrict__ om)
{
    int i = blockIdx.x * 256 + threadIdx.x;
    if (i >= n) return;
    float x = src[i];
    unsigned short h = f2bf(x);
    oh[i] = h; om[i] = f2bf(x - bf2f(h));
}

// ---------------------------------------------------------------------------
// Q/K projection: C = X @ W^T via 6-product 3-way split MFMA (fp32-grade),
// fused RoPE. BM=64 (4 waves x 16 rows), BN=64 = one head. z: 0=Q, 1=K.
// Q out: fp32 (b,h,s,d). K out: bf16 hi/mid + per-wg partial block sums.
__global__ __launch_bounds__(256)
void qk_gemm_k(const unsigned short* __restrict__ Xh,
               const unsigned short* __restrict__ Xm,
               const unsigned short* __restrict__ Xl,
               const unsigned short* __restrict__ Wq3,  // h,m,l consecutive
               const unsigned short* __restrict__ Wk3,
               const float2* __restrict__ tab,
               float* __restrict__ q32,
               unsigned short* __restrict__ kh, unsigned short* __restrict__ km,
               float* __restrict__ partial)
{
    const int z  = blockIdx.z;
    const int h  = blockIdx.x;
    const int n0 = h * 64;
    const int m0 = blockIdx.y * 64;
    const int tid = threadIdx.x;
    const int w = tid >> 6, lane = tid & 63;
    const int col = lane & 15, quad = lane >> 4;

    const unsigned short* W3 = z ? Wk3 : Wq3;
    const unsigned short* B0 = W3;                        // hi
    const unsigned short* B1 = W3 + (size_t)HID*HID;      // mid
    const unsigned short* B2 = B1 + (size_t)HID*HID;      // lo

    const size_t aoff = (size_t)(m0 + w*16 + col) * HID + quad * 8;
    const size_t boff = (size_t)(n0 + col) * HID + quad * 8;

    v4f acc[4] = {};
    #pragma unroll 2
    for (int k0 = 0; k0 < HID; k0 += 32) {
        v8bf a0 = ldbf8(Xh + aoff + k0);
        v8bf a1 = ldbf8(Xm + aoff + k0);
        v8bf a2 = ldbf8(Xl + aoff + k0);
        #pragma unroll
        for (int nt = 0; nt < 4; nt++) {
            const size_t bo = boff + (size_t)nt*16*HID + k0;
            v8bf b0 = ldbf8(B0 + bo);
            v8bf b1 = ldbf8(B1 + bo);
            v8bf b2 = ldbf8(B2 + bo);
            v4f c = acc[nt];
            c = __builtin_amdgcn_mfma_f32_16x16x32_bf16(a0, b0, c, 0,0,0);
            c = __builtin_amdgcn_mfma_f32_16x16x32_bf16(a0, b1, c, 0,0,0);
            c = __builtin_amdgcn_mfma_f32_16x16x32_bf16(a1, b0, c, 0,0,0);
            c = __builtin_amdgcn_mfma_f32_16x16x32_bf16(a0, b2, c, 0,0,0);
            c = __builtin_amdgcn_mfma_f32_16x16x32_bf16(a1, b1, c, 0,0,0);
            c = __builtin_amdgcn_mfma_f32_16x16x32_bf16(a2, b0, c, 0,0,0);
            acc[nt] = c;
        }
    }

    // ---- RoPE epilogue (partner dim d^32 lives in acc[nt^2], same lane)
    const int b = m0 >> 11;
    float vsum[4] = {0.f, 0.f, 0.f, 0.f};
    #pragma unroll
    for (int nt = 0; nt < 4; nt++) {
        const int d = nt*16 + col;
        #pragma unroll
        for (int r = 0; r < 4; r++) {
            const int m = m0 + w*16 + quad*4 + r;
            const int s = m & (SEQN-1);
            float part = acc[nt^2][r];
            float2 sc = tab[(s << 5) + (d & 31)];
            float val = (d < 32) ? acc[nt][r]*sc.y - part*sc.x
                                 : acc[nt][r]*sc.y + part*sc.x;
            const size_t idx = (((size_t)b*NH + h)*SEQN + s)*DH + d;
            if (z == 0) {
                q32[idx] = val;
            } else {
                unsigned short hb = f2bf(val);
                kh[idx] = hb;
                km[idx] = f2bf(val - bf2f(hb));
                vsum[nt] += val;
            }
        }
    }
    if (z == 1) {   // deterministic per-wg block-sum partials
        __shared__ float psum[4][64];
        #pragma unroll
        for (int nt = 0; nt < 4; nt++) {
            float v = vsum[nt];
            v += __shfl_xor(v, 16);
            v += __shfl_xor(v, 32);
            if (quad == 0) psum[w][nt*16 + col] = v;
        }
        __syncthreads();
        if (tid < 64) {
            float s4 = ((psum[0][tid] + psum[1][tid]) + psum[2][tid]) + psum[3][tid];
            const int n = (m0 & (SEQN-1)) >> 8;
            const int p4 = (m0 >> 6) & 3;
            partial[((((size_t)b*NH + h)*NB + n)*4 + p4)*64 + tid] = s4;
        }
    }
}

// ---------------------------------------------------------------------------
// V projection: 3-product split, output transposed bf16 (b,h,d,s) hi only.
__global__ __launch_bounds__(256)
void v_gemm_k(const unsigned short* __restrict__ Xh,
              const unsigned short* __restrict__ Xm,
              const unsigned short* __restrict__ Wv3,
              unsigned short* __restrict__ vth)
{
    const int h  = blockIdx.x;
    const int n0 = h * 64;
    const int m0 = blockIdx.y * 64;
    const int tid = threadIdx.x;
    const int w = tid >> 6, lane = tid & 63;
    const int col = lane & 15, quad = lane >> 4;

    const unsigned short* B0 = Wv3;
    const unsigned short* B1 = Wv3 + (size_t)HID*HID;

    const size_t aoff = (size_t)(m0 + w*16 + col) * HID + quad * 8;
    const size_t boff = (size_t)(n0 + col) * HID + quad * 8;

    v4f acc[4] = {};
    #pragma unroll 2
    for (int k0 = 0; k0 < HID; k0 += 32) {
        v8bf a0 = ldbf8(Xh + aoff + k0);
        v8bf a1 = ldbf8(Xm + aoff + k0);
        #pragma unroll
        for (int nt = 0; nt < 4; nt++) {
            const size_t bo = boff + (size_t)nt*16*HID + k0;
            v8bf b0 = ldbf8(B0 + bo);
            v8bf b1 = ldbf8(B1 + bo);
            v4f c = acc[nt];
            c = __builtin_amdgcn_mfma_f32_16x16x32_bf16(a0, b0, c, 0,0,0);
            c = __builtin_amdgcn_mfma_f32_16x16x32_bf16(a0, b1, c, 0,0,0);
            c = __builtin_amdgcn_mfma_f32_16x16x32_bf16(a1, b0, c, 0,0,0);
            acc[nt] = c;
        }
    }
    const int b = m0 >> 11;
    #pragma unroll
    for (int nt = 0; nt < 4; nt++) {
        const int d = nt*16 + col;
        #pragma unroll
        for (int r = 0; r < 4; r++) {
            const int m = m0 + w*16 + quad*4 + r;
            const int s = m & (SEQN-1);
            vth[(((size_t)b*NH + h)*DH + d)*SEQN + s] = f2bf(acc[nt][r]);
        }
    }
}

// ---------------------------------------------------------------------------
// Block reps: fp64 reduce of the 4 deterministic partials.
__global__ __launch_bounds__(64)
void reps_reduce_k(const float* __restrict__ partial, float* __restrict__ reps)
{
    const int bhn = blockIdx.x;          // 0..191
    const int d = threadIdx.x;
    const float* p = &partial[(size_t)bhn*4*64 + d];
    double s = (double)p[0] + (double)p[64] + (double)p[128] + (double)p[192];
    reps[(size_t)bhn*64 + d] = (float)(s * (1.0/256.0));
}

// ---------------------------------------------------------------------------
// Top-3 selection, fp64 scores, jax tie-break. grid (16 qchunks, 24 bh) x 128.
__global__ __launch_bounds__(128)
void select_topk_k(const float* __restrict__ qg, const float* __restrict__ reps,
                   unsigned* __restrict__ selm)
{
    __shared__ float rs[NB][DH];
    const int bh = blockIdx.y;
    const int tid = threadIdx.x;
    for (int idx = tid; idx < NB*DH; idx += 128)
        rs[idx >> 6][idx & 63] = reps[(size_t)bh*NB*DH + idx];
    __syncthreads();

    const int qq = blockIdx.x * 128 + tid;
    const float* qv = &qg[((size_t)bh*SEQN + qq)*DH];
    float qr[DH];
    #pragma unroll
    for (int c = 0; c < 16; c++) {
        float4 t = *(const float4*)&qv[c*4];
        qr[c*4+0]=t.x; qr[c*4+1]=t.y; qr[c*4+2]=t.z; qr[c*4+3]=t.w;
    }
    const int cur = qq >> 8;
    double sc[NB];
    #pragma unroll
    for (int n = 0; n < NB; n++) {
        double ssum = 0.0;
        for (int d = 0; d < DH; d++) ssum += (double)qr[d] * (double)rs[n][d];
        sc[n] = ssum * 0.125;
    }
    for (int n = cur + 1; n < NB; n++) sc[n] = -1e300;
    sc[cur] = 1e300;
    unsigned mask = 0;
    for (int p = 0; p < 3; p++) {
        int bi = -1; double bv = 0.0;
        for (int n = 0; n < NB; n++) {
            if ((mask >> n) & 1) continue;
            if (bi < 0 || sc[n] > bv) { bi = n; bv = sc[n]; }
        }
        mask |= 1u << bi;
    }
    selm[(size_t)bh*SEQN + qq] = mask;
}

// ---------------------------------------------------------------------------
// MFMA flash attention. 128 thr = 2 independent wave-tiles of 16 queries.
// Grid 1536 with XCD-local bh mapping (id&7 -> 3 bh's per XCD).
// S: 3-product split (q split in-kernel from fp32). PV: (Ph+Pl)*Vh.
__global__ __launch_bounds__(128)
void moba_attn_k(const float* __restrict__ q32,
                 const unsigned short* __restrict__ kh,
                 const unsigned short* __restrict__ km,
                 const unsigned short* __restrict__ vth,
                 const unsigned* __restrict__ selm,
                 unsigned short* __restrict__ aoh,
                 unsigned short* __restrict__ aom)
{
    __shared__ unsigned short plds[2][2][16][72];

    const int id    = blockIdx.x;
    const int local = id >> 3;
    const int bh    = (id & 7) * 3 + (local >> 6);   // 24 bh over 8 XCDs
    const int t2    = local & 63;
    const int tid   = threadIdx.x;
    const int wave  = tid >> 6;
    const int lane  = tid & 63;
    const int col   = lane & 15, quad = lane >> 4;
    const int qw0   = (t2 * 2 + wave) * 16;
    const int cur   = qw0 >> 8;
    const size_t bhS = (size_t)bh * SEQN;

    const unsigned mymask = selm[bhS + qw0 + col];
    unsigned uni = mymask;
    #pragma unroll
    for (int off = 1; off < 16; off <<= 1) uni |= __shfl_xor(uni, off, 16);

    // Q B-fragments: split fp32 -> (hi, lo) bf16 in-register
    v8bf qh[2], ql[2];
    #pragma unroll
    for (int ks = 0; ks < 2; ks++) {
        const float* qp = &q32[(bhS + qw0 + col)*DH + ks*32 + quad*8];
        float4 f0 = *(const float4*)qp;
        float4 f1 = *(const float4*)(qp + 4);
        float qf[8] = {f0.x,f0.y,f0.z,f0.w,f1.x,f1.y,f1.z,f1.w};
        BF8 uh, ul;
        #pragma unroll
        for (int j = 0; j < 8; j++) {
            unsigned short hb = f2bf(qf[j]);
            uh.u[j] = hb;
            ul.u[j] = f2bf(qf[j] - bf2f(hb));
        }
        qh[ks] = uh.b; ql[ks] = ul.b;
    }

    const v4f zero4 = {0.f, 0.f, 0.f, 0.f};
    v4f oacc[4] = {zero4, zero4, zero4, zero4};
    float m_i = NEG_INF, l_i = 0.f;
    const int qpos = qw0 + col;
    const bool iscur_any = true;

    for (int n = 0; n < NB; n++) {
        if (!((uni >> n) & 1)) continue;
        const bool iscur = (n == cur);
        const bool selq  = (mymask >> n) & 1;
        for (int c2 = 0; c2 < 4; c2++) {
            const int kb = n * BLKSZ + c2 * 64;

            // ---- S^T[64k x 16q], 3-product split
            v4f sf[4];
            #pragma unroll
            for (int mt = 0; mt < 4; mt++) {
                const size_t kbase = (bhS + kb + mt*16 + col) * DH + quad * 8;
                v8bf ah0 = ldbf8(kh + kbase);
                v8bf ah1 = ldbf8(kh + kbase + 32);
                v8bf al0 = ldbf8(km + kbase);
                v8bf al1 = ldbf8(km + kbase + 32);
                v4f c = zero4;
                c = __builtin_amdgcn_mfma_f32_16x16x32_bf16(ah0, qh[0], c, 0,0,0);
                c = __builtin_amdgcn_mfma_f32_16x16x32_bf16(ah1, qh[1], c, 0,0,0);
                c = __builtin_amdgcn_mfma_f32_16x16x32_bf16(ah0, ql[0], c, 0,0,0);
                c = __builtin_amdgcn_mfma_f32_16x16x32_bf16(ah1, ql[1], c, 0,0,0);
                c = __builtin_amdgcn_mfma_f32_16x16x32_bf16(al0, qh[0], c, 0,0,0);
                c = __builtin_amdgcn_mfma_f32_16x16x32_bf16(al1, qh[1], c, 0,0,0);
                sf[mt] = c;
            }

            // ---- mask + scale + row max (row = query = lane col)
            float rm = NEG_INF;
            #pragma unroll
            for (int mt = 0; mt < 4; mt++)
                #pragma unroll
                for (int r = 0; r < 4; r++) {
                    const int kidx = kb + mt*16 + quad*4 + r;
                    const bool ok = selq && (!iscur || kidx <= qpos);
                    float f = ok ? sf[mt][r] * 0.125f : NEG_INF;
                    sf[mt][r] = f;
                    rm = fmaxf(rm, f);
                }
            rm = fmaxf(rm, __shfl_xor(rm, 16));
            rm = fmaxf(rm, __shfl_xor(rm, 32));
            const float mnew  = fmaxf(m_i, rm);
            const float alpha = (m_i == NEG_INF) ? 0.f : __expf(m_i - mnew);
            const float mex   = (mnew == NEG_INF) ? 0.f : mnew;

            // ---- exp -> split P into LDS (A-layout rows = query)
            float lsum = 0.f;
            #pragma unroll
            for (int mt = 0; mt < 4; mt++)
                #pragma unroll
                for (int r = 0; r < 4; r++) {
                    float p = __expf(sf[mt][r] - mex);
                    lsum += p;
                    unsigned short ph = f2bf(p);
                    plds[wave][0][col][mt*16 + quad*4 + r] = ph;
                    plds[wave][1][col][mt*16 + quad*4 + r] = f2bf(p - bf2f(ph));
                }
            lsum += __shfl_xor(lsum, 16);
            lsum += __shfl_xor(lsum, 32);
            l_i = l_i * alpha + lsum;
            m_i = mnew;

            // ---- rescale O rows
            float ar[4];
            #pragma unroll
            for (int r = 0; r < 4; r++) ar[r] = __shfl(alpha, quad*4 + r, 16);
            #pragma unroll
            for (int nt = 0; nt < 4; nt++)
                #pragma unroll
                for (int r = 0; r < 4; r++) oacc[nt][r] *= ar[r];

            __threadfence_block();

            // ---- O += (Ph + Pl) * Vh
            #pragma unroll
            for (int ks2 = 0; ks2 < 2; ks2++) {
                v8bf ph = ldbf8(&plds[wave][0][col][ks2*32 + quad*8]);
                v8bf pl = ldbf8(&plds[wave][1][col][ks2*32 + quad*8]);
                #pragma unroll
                for (int nt = 0; nt < 4; nt++) {
                    const size_t vb = ((size_t)bh*DH + nt*16 + col) * SEQN
                                    + kb + ks2*32 + quad*8;
                    v8bf vh = ldbf8(vth + vb);
                    oacc[nt] = __builtin_amdgcn_mfma_f32_16x16x32_bf16(ph, vh, oacc[nt], 0,0,0);
                    oacc[nt] = __builtin_amdgcn_mfma_f32_16x16x32_bf16(pl, vh, oacc[nt], 0,0,0);
                }
            }
        }
    }

    // ---- epilogue: normalize, write 2-way bf16 split of attn-out
    const int b = bh / NH, h = bh % NH;
    const float invl = 1.f / l_i;
    float ir[4];
    #pragma unroll
    for (int r = 0; r < 4; r++) ir[r] = __shfl(invl, quad*4 + r, 16);
    #pragma unroll
    for (int nt = 0; nt < 4; nt++)
        #pragma unroll
        for (int r = 0; r < 4; r++) {
            const int qi = qw0 + quad*4 + r;
            const size_t idx = ((size_t)b*SEQN + qi)*HID + h*DH + nt*16 + col;
            float val = oacc[nt][r] * ir[r];
            unsigned short hb = f2bf(val);
            aoh[idx] = hb;
            aom[idx] = f2bf(val - bf2f(hb));
        }
}

// ---------------------------------------------------------------------------
// Output projection: 3-product split MFMA, fp32 store.
__global__ __launch_bounds__(256)
void out_gemm_k(const unsigned short* __restrict__ Ah,
                const unsigned short* __restrict__ Am,
                const unsigned short* __restrict__ Wo2,
                float* __restrict__ C)
{
    const int n0 = blockIdx.x * 64;
    const int m0 = blockIdx.y * 64;
    const int tid = threadIdx.x;
    const int w = tid >> 6, lane = tid & 63;
    const int col = lane & 15, quad = lane >> 4;

    const unsigned short* B0 = Wo2;
    const unsigned short* B1 = Wo2 + (size_t)HID*HID;

    const size_t aoff = (size_t)(m0 + w*16 + col) * HID + quad * 8;
    const size_t boff = (size_t)(n0 + col) * HID + quad * 8;

    v4f acc[4] = {};
    #pragma unroll 2
    for (int k0 = 0; k0 < HID; k0 += 32) {
        v8bf a0 = ldbf8(Ah + aoff + k0);
        v8bf a1 = ldbf8(Am + aoff + k0);
        #pragma unroll
        for (int nt = 0; nt < 4; nt++) {
            const size_t bo = boff + (size_t)nt*16*HID + k0;
            v8bf b0 = ldbf8(B0 + bo);
            v8bf b1 = ldbf8(B1 + bo);
            v4f c = acc[nt];
            c = __builtin_amdgcn_mfma_f32_16x16x32_bf16(a0, b0, c, 0,0,0);
            c = __builtin_amdgcn_mfma_f32_16x16x32_bf16(a0, b1, c, 0,0,0);
            c = __builtin_amdgcn_mfma_f32_16x16x32_bf16(a1, b0, c, 0,0,0);
            acc[nt] = c;
        }
    }
    #pragma unroll
    for (int nt = 0; nt < 4; nt++)
        #pragma unroll
        for (int r = 0; r < 4; r++) {
            const int m = m0 + w*16 + quad*4 + r;
            C[(size_t)m*HID + n0 + nt*16 + col] = acc[nt][r];
        }
}

// ---------------------------------------------------------------------------
extern "C" void kernel_launch(void* const* d_in, const int* in_sizes, int n_in,
                              void* d_out, int out_size, void* d_ws, size_t ws_size,
                              hipStream_t stream)
{
    const float* X  = (const float*)d_in[0];
    const float* Wq = (const float*)d_in[1];
    const float* Wk = (const float*)d_in[2];
    const float* Wv = (const float*)d_in[3];
    const float* Wo = (const float*)d_in[4];
    float* out = (float*)d_out;

    char* p = (char*)d_ws;
    float* q32 = (float*)p;                          p += (size_t)NTOK*HID*4;   // 12.58 MB
    unsigned short* kh  = (unsigned short*)p;        p += (size_t)NTOK*HID*2;
    unsigned short* km  = (unsigned short*)p;        p += (size_t)NTOK*HID*2;
    unsigned short* vth = (unsigned short*)p;        p += (size_t)NTOK*HID*2;
    unsigned short* Xh  = (unsigned short*)p;        p += (size_t)NTOK*HID*2;   // aoh aliases
    unsigned short* Xm  = (unsigned short*)p;        p += (size_t)NTOK*HID*2;   // aom aliases
    unsigned short* Xl  = (unsigned short*)p;        p += (size_t)NTOK*HID*2;
    unsigned short* Wq3 = (unsigned short*)p;        p += (size_t)HID*HID*2*3;
    unsigned short* Wk3 = (unsigned short*)p;        p += (size_t)HID*HID*2*3;
    unsigned short* Wv3 = (unsigned short*)p;        p += (size_t)HID*HID*2*3;
    unsigned short* Wo2 = (unsigned short*)p;        p += (size_t)HID*HID*2*2;
    float* partial = (float*)p;                      p += (size_t)BATCH*NH*NB*4*64*4;
    float* reps    = (float*)p;                      p += (size_t)BATCH*NH*NB*DH*4;
    unsigned* selm = (unsigned*)p;                   p += (size_t)BATCH*NH*SEQN*4;
    float2* tab    = (float2*)p;                     p += (size_t)SEQN*32*8;
    // total ~64.3 MB
    unsigned short* aoh = Xh;   // X splits dead after projections
    unsigned short* aom = Xm;

    const int NX = NTOK*HID;          // 3,145,728
    const int NW = HID*HID;           // 589,824

    rope_tab_k<<<dim3((SEQN*32+255)/256), 256, 0, stream>>>(tab);
    split3_k<<<dim3((NX+255)/256), 256, 0, stream>>>(X,  NX, Xh, Xm, Xl);
    split3_k<<<dim3((NW+255)/256), 256, 0, stream>>>(Wq, NW, Wq3, Wq3+NW, Wq3+2*NW);
    split3_k<<<dim3((NW+255)/256), 256, 0, stream>>>(Wk, NW, Wk3, Wk3+NW, Wk3+2*NW);
    split3_k<<<dim3((NW+255)/256), 256, 0, stream>>>(Wv, NW, Wv3, Wv3+NW, Wv3+2*NW);
    split2_k<<<dim3((NW+255)/256), 256, 0, stream>>>(Wo, NW, Wo2, Wo2+NW);

    qk_gemm_k<<<dim3(NH, NTOK/64, 2), 256, 0, stream>>>(
        Xh, Xm, Xl, Wq3, Wk3, tab, q32, kh, km, partial);
    v_gemm_k <<<dim3(NH, NTOK/64),    256, 0, stream>>>(Xh, Xm, Wv3, vth);

    reps_reduce_k<<<dim3(BATCH*NH*NB), 64, 0, stream>>>(partial, reps);
    select_topk_k<<<dim3(SEQN/128, BATCH*NH), 128, 0, stream>>>(q32, reps, selm);

    moba_attn_k<<<dim3(BATCH*NH*(SEQN/16)/2), 128, 0, stream>>>(
        q32, kh, km, vth, selm, aoh, aom);

    out_gemm_k<<<dim3(HID/64, NTOK/64), 256, 0, stream>>>(aoh, aom, Wo2, out);
}

// Round 4
// 418.440 us; speedup vs baseline: 3.3915x; 1.6827x over previous
//
#include <hip/hip_runtime.h>
#include <math.h>

// MoBA attention, round 3: LDS-staged (global_load_lds) 128x128 MFMA GEMM
// for all projections, concat-K split-product encoding, XCD-partitioned grid.
// Attention/selection kernels unchanged from round 2 (passing).

#define HID   768
#define NH    12
#define DH    64
#define SEQN  2048
#define BATCH 2
#define NTOK  (BATCH*SEQN)   // 4096
#define NB    8
#define BLKSZ 256
#define NEG_INF (-__builtin_huge_valf())

typedef unsigned short u16;
typedef __bf16 v8bf __attribute__((ext_vector_type(8)));
typedef unsigned short v8us __attribute__((ext_vector_type(8)));
typedef float  v4f  __attribute__((ext_vector_type(4)));

union BF8 { v8us u; v8bf b; };

__device__ __forceinline__ u16 f2bf(float f) {
    unsigned u = __builtin_bit_cast(unsigned, f);
    u = (u + 0x7fffu + ((u >> 16) & 1u)) >> 16;      // RNE
    return (u16)u;
}
__device__ __forceinline__ float bf2f(u16 h) {
    unsigned u = ((unsigned)h) << 16;
    return __builtin_bit_cast(float, u);
}
__device__ __forceinline__ v8bf ldbf8(const u16* p) {
    return *reinterpret_cast<const v8bf*>(p);
}
// async global->LDS, 16B per lane; lds ptr must be wave-uniform base.
__device__ __forceinline__ void g2lds16(const u16* g, u16* l) {
    __builtin_amdgcn_global_load_lds(
        (const __attribute__((address_space(1))) void*)g,
        (__attribute__((address_space(3))) void*)l, 16, 0, 0);
}

// ---------------------------------------------------------------------------
// RoPE table: fp32 angle (numpy op order), fp64 trig, round to fp32.
__global__ __launch_bounds__(256)
void rope_tab_k(float2* __restrict__ tab)
{
    int i = blockIdx.x * 256 + threadIdx.x;
    if (i >= SEQN * 32) return;
    int s = i >> 5, f = i & 31;
    double y  = exp((double)f * (log(10000.0) / 32.0));
    float  yf = (float)y;
    float  invf = 1.0f / yf;
    float  ang  = (float)s * invf;
    tab[i] = make_float2((float)sin((double)ang), (float)cos((double)ang));
}

// ---------------------------------------------------------------------------
// fp32 -> 3-way / 2-way bf16 splits.
__global__ __launch_bounds__(256)
void split3_k(const float* __restrict__ src, int n,
              u16* __restrict__ oh, u16* __restrict__ om, u16* __restrict__ ol)
{
    int i = blockIdx.x * 256 + threadIdx.x;
    if (i >= n) return;
    float x = src[i];
    u16 h = f2bf(x);
    float r1 = x - bf2f(h);
    u16 m = f2bf(r1);
    float r2 = r1 - bf2f(m);
    oh[i] = h; om[i] = m; ol[i] = f2bf(r2);
}

__global__ __launch_bounds__(256)
void split2_k(const float* __restrict__ src, int n,
              u16* __restrict__ oh, u16* __restrict__ om)
{
    int i = blockIdx.x * 256 + threadIdx.x;
    if (i >= n) return;
    float x = src[i];
    u16 h = f2bf(x);
    oh[i] = h; om[i] = f2bf(x - bf2f(h));
}

// ---------------------------------------------------------------------------
// Shared 128x128 tile mainloop. C[m][n] = sum_c sum_k Apl[asel[c]][m][k] *
// Bpl[bsel[c]][n][k]. LDS XOR-swizzled granules (16B), global_load_lds wide.
// 256 thr = 4 waves in 2x2, each 64x64 (4x4 MFMAs 16x16x32).
__device__ __forceinline__
void gemm_mainloop(const u16* __restrict__ Abase, size_t aps,
                   const u16* __restrict__ Bbase,
                   int m0, int nb0, int nchunks,
                   u16* As, u16* Bs, v4f acc[4][4])
{
    const int asel_[6] = {0, 0, 1, 0, 1, 2};
    const int bsel_[6] = {0, 1, 0, 2, 1, 0};
    const int tid  = threadIdx.x;
    const int wave = tid >> 6, lane = tid & 63;
    const int col  = lane & 15, quad = lane >> 4;
    const int wr   = wave >> 1, wc = wave & 1;

    int ld_row[4], ld_gl[4];
    #pragma unroll
    for (int r = 0; r < 4; r++) {
        int g = r * 256 + tid;           // granule index 0..1023
        ld_row[r] = g >> 3;              // LDS row 0..127
        ld_gl[r]  = (g & 7) ^ (ld_row[r] & 7);  // global granule (swizzle)
    }

    for (int c = 0; c < nchunks; c++) {
        const u16* Ap = Abase + (size_t)asel_[c] * aps;
        const u16* Bp = Bbase + (size_t)bsel_[c] * (HID * HID);
        for (int itc = 0; itc < HID / 64; itc++) {
            const int k0 = itc * 64;
            __syncthreads();
            #pragma unroll
            for (int r = 0; r < 4; r++) {
                g2lds16(Ap + (size_t)(m0 + ld_row[r]) * HID + k0 + ld_gl[r] * 8,
                        &As[(r * 256 + wave * 64) * 8]);
                g2lds16(Bp + (size_t)(nb0 + ld_row[r]) * HID + k0 + ld_gl[r] * 8,
                        &Bs[(r * 256 + wave * 64) * 8]);
            }
            __syncthreads();
            #pragma unroll
            for (int ks = 0; ks < 2; ks++) {
                v8bf af[4], bf_[4];
                #pragma unroll
                for (int mt = 0; mt < 4; mt++) {
                    const int row = wr * 64 + mt * 16 + col;
                    const int gph = (ks * 4 + quad) ^ (row & 7);
                    af[mt] = ldbf8(&As[row * 64 + gph * 8]);
                }
                #pragma unroll
                for (int nt = 0; nt < 4; nt++) {
                    const int row = wc * 64 + nt * 16 + col;
                    const int gph = (ks * 4 + quad) ^ (row & 7);
                    bf_[nt] = ldbf8(&Bs[row * 64 + gph * 8]);
                }
                #pragma unroll
                for (int mt = 0; mt < 4; mt++)
                    #pragma unroll
                    for (int nt = 0; nt < 4; nt++)
                        acc[mt][nt] = __builtin_amdgcn_mfma_f32_16x16x32_bf16(
                            af[mt], bf_[nt], acc[mt][nt], 0, 0, 0);
            }
        }
    }
    __syncthreads();
}

// ---------------------------------------------------------------------------
// Fused QKV projection. grid = 576: 18 n-tiles (Q 0-5, K 6-11, V 12-17) x
// 32 m-tiles, XCD-partitioned by m. Epilogue per matrix.
__global__ __launch_bounds__(256)
void qkv_fused_gemm_k(const u16* __restrict__ A3,
                      const u16* __restrict__ Wq3, const u16* __restrict__ Wk3,
                      const u16* __restrict__ Wv3, const float2* __restrict__ tab,
                      float* __restrict__ q32,
                      u16* __restrict__ kh, u16* __restrict__ km,
                      u16* __restrict__ vth, float* __restrict__ partial)
{
    __shared__ u16 As[128 * 64];
    __shared__ u16 Bs[128 * 64];
    __shared__ float psum[2][2][64];

    const int id    = blockIdx.x;
    const int xcd   = id & 7, loc = id >> 3;          // 72 blocks per XCD
    const int mtile = xcd * 4 + (loc & 3);            // 4 m-tiles per XCD
    const int ntile = loc >> 2;                       // 0..17
    const int m0 = mtile * 128;
    const int n0 = ntile * 128;
    const int mat = n0 / HID;                         // 0=Q 1=K 2=V
    const int nb0 = n0 - mat * HID;
    const u16* Bbase = (mat == 0) ? Wq3 : (mat == 1) ? Wk3 : Wv3;
    const int nchunks = (mat == 2) ? 3 : 6;

    v4f acc[4][4] = {};
    gemm_mainloop(A3, (size_t)NTOK * HID, Bbase, m0, nb0, nchunks, As, Bs, acc);

    const int tid  = threadIdx.x;
    const int wave = tid >> 6, lane = tid & 63;
    const int col  = lane & 15, quad = lane >> 4;
    const int wr   = wave >> 1, wc = wave & 1;
    const int b    = m0 >> 11;
    const int h    = (nb0 + wc * 64) >> 6;
    const size_t bh = (size_t)b * NH + h;

    if (mat == 2) {                       // ---- V: transposed bf16-hi store
        #pragma unroll
        for (int nt = 0; nt < 4; nt++) {
            const int d = nt * 16 + col;
            #pragma unroll
            for (int mt = 0; mt < 4; mt++) {
                const int m = m0 + wr * 64 + mt * 16 + quad * 4;
                const int s = m & (SEQN - 1);
                ushort4 pk = make_ushort4(f2bf(acc[mt][nt][0]), f2bf(acc[mt][nt][1]),
                                          f2bf(acc[mt][nt][2]), f2bf(acc[mt][nt][3]));
                *(ushort4*)&vth[(bh * DH + d) * SEQN + s] = pk;
            }
        }
        return;
    }

    // ---- Q/K: RoPE (partner dim d^32 = acc[mt][nt^2], same lane)
    float vsum[4] = {0.f, 0.f, 0.f, 0.f};
    #pragma unroll
    for (int mt = 0; mt < 4; mt++) {
        #pragma unroll
        for (int nt = 0; nt < 4; nt++) {
            const int d = nt * 16 + col;
            #pragma unroll
            for (int r = 0; r < 4; r++) {
                const int m = m0 + wr * 64 + mt * 16 + quad * 4 + r;
                const int s = m & (SEQN - 1);
                const float part = acc[mt][nt ^ 2][r];
                const float2 sc = tab[(s << 5) + (d & 31)];
                const float val = (d < 32) ? acc[mt][nt][r] * sc.y - part * sc.x
                                           : acc[mt][nt][r] * sc.y + part * sc.x;
                const size_t idx = (bh * SEQN + s) * DH + d;
                if (mat == 0) {
                    q32[idx] = val;
                } else {
                    u16 hb = f2bf(val);
                    kh[idx] = hb;
                    km[idx] = f2bf(val - bf2f(hb));
                    vsum[nt] += val;
                }
            }
        }
    }
    if (mat == 1) {                      // ---- per-wg 128-token block partials
        #pragma unroll
        for (int nt = 0; nt < 4; nt++) {
            float v = vsum[nt];
            v += __shfl_xor(v, 16);
            v += __shfl_xor(v, 32);
            if (quad == 0) psum[wr][wc][nt * 16 + col] = v;
        }
        __syncthreads();
        if (tid < 128) {
            const int wc2 = tid >> 6, d = tid & 63;
            const float s2 = psum[0][wc2][d] + psum[1][wc2][d];
            const int h2 = (nb0 + wc2 * 64) >> 6;
            const int nblk = (m0 & (SEQN - 1)) >> 8;
            const int half = (m0 >> 7) & 1;
            partial[((((size_t)b * NH + h2) * NB + nblk) * 2 + half) * 64 + d] = s2;
        }
    }
}

// ---------------------------------------------------------------------------
// Output projection: same mainloop, fp32 store to d_out. grid = 192.
__global__ __launch_bounds__(256)
void out_gemm_mfma_k(const u16* __restrict__ A2, const u16* __restrict__ Wo2,
                     float* __restrict__ C)
{
    __shared__ u16 As[128 * 64];
    __shared__ u16 Bs[128 * 64];

    const int id    = blockIdx.x;
    const int xcd   = id & 7, loc = id >> 3;          // 24 per XCD
    const int mtile = xcd * 4 + (loc & 3);
    const int ntile = loc >> 2;                       // 0..5
    const int m0 = mtile * 128;
    const int n0 = ntile * 128;

    v4f acc[4][4] = {};
    gemm_mainloop(A2, (size_t)NTOK * HID, Wo2, m0, n0, 3, As, Bs, acc);

    const int tid  = threadIdx.x;
    const int wave = tid >> 6, lane = tid & 63;
    const int col  = lane & 15, quad = lane >> 4;
    const int wr   = wave >> 1, wc = wave & 1;

    #pragma unroll
    for (int mt = 0; mt < 4; mt++)
        #pragma unroll
        for (int nt = 0; nt < 4; nt++)
            #pragma unroll
            for (int r = 0; r < 4; r++) {
                const int m = m0 + wr * 64 + mt * 16 + quad * 4 + r;
                C[(size_t)m * HID + n0 + wc * 64 + nt * 16 + col] = acc[mt][nt][r];
            }
}

// ---------------------------------------------------------------------------
// Block reps: fp64 reduce of the 2 deterministic 128-token partials.
__global__ __launch_bounds__(64)
void reps_reduce_k(const float* __restrict__ partial, float* __restrict__ reps)
{
    const int bhn = blockIdx.x;          // 0..191
    const int d = threadIdx.x;
    const float* p = &partial[(size_t)bhn * 128 + d];
    double s = (double)p[0] + (double)p[64];
    reps[(size_t)bhn * 64 + d] = (float)(s * (1.0 / 256.0));
}

// ---------------------------------------------------------------------------
// Top-3 selection, fp64 scores, jax tie-break.
__global__ __launch_bounds__(128)
void select_topk_k(const float* __restrict__ qg, const float* __restrict__ reps,
                   unsigned* __restrict__ selm)
{
    __shared__ float rs[NB][DH];
    const int bh = blockIdx.y;
    const int tid = threadIdx.x;
    for (int idx = tid; idx < NB * DH; idx += 128)
        rs[idx >> 6][idx & 63] = reps[(size_t)bh * NB * DH + idx];
    __syncthreads();

    const int qq = blockIdx.x * 128 + tid;
    const float* qv = &qg[((size_t)bh * SEQN + qq) * DH];
    float qr[DH];
    #pragma unroll
    for (int c = 0; c < 16; c++) {
        float4 t = *(const float4*)&qv[c * 4];
        qr[c*4+0]=t.x; qr[c*4+1]=t.y; qr[c*4+2]=t.z; qr[c*4+3]=t.w;
    }
    const int cur = qq >> 8;
    double sc[NB];
    #pragma unroll
    for (int n = 0; n < NB; n++) {
        double ssum = 0.0;
        for (int d = 0; d < DH; d++) ssum += (double)qr[d] * (double)rs[n][d];
        sc[n] = ssum * 0.125;
    }
    for (int n = cur + 1; n < NB; n++) sc[n] = -1e300;
    sc[cur] = 1e300;
    unsigned mask = 0;
    for (int p = 0; p < 3; p++) {
        int bi = -1; double bv = 0.0;
        for (int n = 0; n < NB; n++) {
            if ((mask >> n) & 1) continue;
            if (bi < 0 || sc[n] > bv) { bi = n; bv = sc[n]; }
        }
        mask |= 1u << bi;
    }
    selm[(size_t)bh * SEQN + qq] = mask;
}

// ---------------------------------------------------------------------------
// MFMA flash attention (round-2 structure, unchanged).
__global__ __launch_bounds__(128)
void moba_attn_k(const float* __restrict__ q32,
                 const u16* __restrict__ kh, const u16* __restrict__ km,
                 const u16* __restrict__ vth, const unsigned* __restrict__ selm,
                 u16* __restrict__ aoh, u16* __restrict__ aom)
{
    __shared__ u16 plds[2][2][16][72];

    const int id    = blockIdx.x;
    const int local = id >> 3;
    const int bh    = (id & 7) * 3 + (local >> 6);
    const int t2    = local & 63;
    const int tid   = threadIdx.x;
    const int wave  = tid >> 6;
    const int lane  = tid & 63;
    const int col   = lane & 15, quad = lane >> 4;
    const int qw0   = (t2 * 2 + wave) * 16;
    const int cur   = qw0 >> 8;
    const size_t bhS = (size_t)bh * SEQN;

    const unsigned mymask = selm[bhS + qw0 + col];
    unsigned uni = mymask;
    #pragma unroll
    for (int off = 1; off < 16; off <<= 1) uni |= __shfl_xor(uni, off, 16);

    v8bf qh[2], ql[2];
    #pragma unroll
    for (int ks = 0; ks < 2; ks++) {
        const float* qp = &q32[(bhS + qw0 + col) * DH + ks * 32 + quad * 8];
        float4 f0 = *(const float4*)qp;
        float4 f1 = *(const float4*)(qp + 4);
        float qf[8] = {f0.x, f0.y, f0.z, f0.w, f1.x, f1.y, f1.z, f1.w};
        BF8 uh, ul;
        #pragma unroll
        for (int j = 0; j < 8; j++) {
            u16 hb = f2bf(qf[j]);
            uh.u[j] = hb;
            ul.u[j] = f2bf(qf[j] - bf2f(hb));
        }
        qh[ks] = uh.b; ql[ks] = ul.b;
    }

    const v4f zero4 = {0.f, 0.f, 0.f, 0.f};
    v4f oacc[4] = {zero4, zero4, zero4, zero4};
    float m_i = NEG_INF, l_i = 0.f;
    const int qpos = qw0 + col;

    for (int n = 0; n < NB; n++) {
        if (!((uni >> n) & 1)) continue;
        const bool iscur = (n == cur);
        const bool selq  = (mymask >> n) & 1;
        for (int c2 = 0; c2 < 4; c2++) {
            const int kb = n * BLKSZ + c2 * 64;

            v4f sf[4];
            #pragma unroll
            for (int mt = 0; mt < 4; mt++) {
                const size_t kbase = (bhS + kb + mt * 16 + col) * DH + quad * 8;
                v8bf ah0 = ldbf8(kh + kbase);
                v8bf ah1 = ldbf8(kh + kbase + 32);
                v8bf al0 = ldbf8(km + kbase);
                v8bf al1 = ldbf8(km + kbase + 32);
                v4f c = zero4;
                c = __builtin_amdgcn_mfma_f32_16x16x32_bf16(ah0, qh[0], c, 0,0,0);
                c = __builtin_amdgcn_mfma_f32_16x16x32_bf16(ah1, qh[1], c, 0,0,0);
                c = __builtin_amdgcn_mfma_f32_16x16x32_bf16(ah0, ql[0], c, 0,0,0);
                c = __builtin_amdgcn_mfma_f32_16x16x32_bf16(ah1, ql[1], c, 0,0,0);
                c = __builtin_amdgcn_mfma_f32_16x16x32_bf16(al0, qh[0], c, 0,0,0);
                c = __builtin_amdgcn_mfma_f32_16x16x32_bf16(al1, qh[1], c, 0,0,0);
                sf[mt] = c;
            }

            float rm = NEG_INF;
            #pragma unroll
            for (int mt = 0; mt < 4; mt++)
                #pragma unroll
                for (int r = 0; r < 4; r++) {
                    const int kidx = kb + mt * 16 + quad * 4 + r;
                    const bool ok = selq && (!iscur || kidx <= qpos);
                    float f = ok ? sf[mt][r] * 0.125f : NEG_INF;
                    sf[mt][r] = f;
                    rm = fmaxf(rm, f);
                }
            rm = fmaxf(rm, __shfl_xor(rm, 16));
            rm = fmaxf(rm, __shfl_xor(rm, 32));
            const float mnew  = fmaxf(m_i, rm);
            const float alpha = (m_i == NEG_INF) ? 0.f : __expf(m_i - mnew);
            const float mex   = (mnew == NEG_INF) ? 0.f : mnew;

            float lsum = 0.f;
            #pragma unroll
            for (int mt = 0; mt < 4; mt++)
                #pragma unroll
                for (int r = 0; r < 4; r++) {
                    float p = __expf(sf[mt][r] - mex);
                    lsum += p;
                    u16 ph = f2bf(p);
                    plds[wave][0][col][mt * 16 + quad * 4 + r] = ph;
                    plds[wave][1][col][mt * 16 + quad * 4 + r] = f2bf(p - bf2f(ph));
                }
            lsum += __shfl_xor(lsum, 16);
            lsum += __shfl_xor(lsum, 32);
            l_i = l_i * alpha + lsum;
            m_i = mnew;

            float ar[4];
            #pragma unroll
            for (int r = 0; r < 4; r++) ar[r] = __shfl(alpha, quad * 4 + r, 16);
            #pragma unroll
            for (int nt = 0; nt < 4; nt++)
                #pragma unroll
                for (int r = 0; r < 4; r++) oacc[nt][r] *= ar[r];

            __threadfence_block();

            #pragma unroll
            for (int ks2 = 0; ks2 < 2; ks2++) {
                v8bf ph = ldbf8(&plds[wave][0][col][ks2 * 32 + quad * 8]);
                v8bf pl = ldbf8(&plds[wave][1][col][ks2 * 32 + quad * 8]);
                #pragma unroll
                for (int nt = 0; nt < 4; nt++) {
                    const size_t vb = ((size_t)bh * DH + nt * 16 + col) * SEQN
                                    + kb + ks2 * 32 + quad * 8;
                    v8bf vh = ldbf8(vth + vb);
                    oacc[nt] = __builtin_amdgcn_mfma_f32_16x16x32_bf16(ph, vh, oacc[nt], 0,0,0);
                    oacc[nt] = __builtin_amdgcn_mfma_f32_16x16x32_bf16(pl, vh, oacc[nt], 0,0,0);
                }
            }
        }
    }

    const int b = bh / NH, h = bh % NH;
    const float invl = 1.f / l_i;
    float ir[4];
    #pragma unroll
    for (int r = 0; r < 4; r++) ir[r] = __shfl(invl, quad * 4 + r, 16);
    #pragma unroll
    for (int nt = 0; nt < 4; nt++)
        #pragma unroll
        for (int r = 0; r < 4; r++) {
            const int qi = qw0 + quad * 4 + r;
            const size_t idx = ((size_t)b * SEQN + qi) * HID + h * DH + nt * 16 + col;
            float val = oacc[nt][r] * ir[r];
            u16 hb = f2bf(val);
            aoh[idx] = hb;
            aom[idx] = f2bf(val - bf2f(hb));
        }
}

// ---------------------------------------------------------------------------
extern "C" void kernel_launch(void* const* d_in, const int* in_sizes, int n_in,
                              void* d_out, int out_size, void* d_ws, size_t ws_size,
                              hipStream_t stream)
{
    const float* X  = (const float*)d_in[0];
    const float* Wq = (const float*)d_in[1];
    const float* Wk = (const float*)d_in[2];
    const float* Wv = (const float*)d_in[3];
    const float* Wo = (const float*)d_in[4];
    float* out = (float*)d_out;

    char* p = (char*)d_ws;
    float* q32 = (float*)p;                p += (size_t)NTOK*HID*4;
    u16* kh  = (u16*)p;                    p += (size_t)NTOK*HID*2;
    u16* km  = (u16*)p;                    p += (size_t)NTOK*HID*2;
    u16* vth = (u16*)p;                    p += (size_t)NTOK*HID*2;
    u16* Xh  = (u16*)p;                    p += (size_t)NTOK*HID*2;   // aoh alias
    u16* Xm  = (u16*)p;                    p += (size_t)NTOK*HID*2;   // aom alias
    u16* Xl  = (u16*)p;                    p += (size_t)NTOK*HID*2;
    u16* Wq3 = (u16*)p;                    p += (size_t)HID*HID*2*3;
    u16* Wk3 = (u16*)p;                    p += (size_t)HID*HID*2*3;
    u16* Wv3 = (u16*)p;                    p += (size_t)HID*HID*2*3;
    u16* Wo2 = (u16*)p;                    p += (size_t)HID*HID*2*2;
    float* partial = (float*)p;            p += (size_t)BATCH*NH*NB*2*64*4;
    float* reps    = (float*)p;            p += (size_t)BATCH*NH*NB*DH*4;
    unsigned* selm = (unsigned*)p;         p += (size_t)BATCH*NH*SEQN*4;
    float2* tab    = (float2*)p;           p += (size_t)SEQN*32*8;
    u16* aoh = Xh;    // X splits dead after projections
    u16* aom = Xm;

    const int NX = NTOK*HID;          // 3,145,728
    const int NW = HID*HID;           // 589,824

    rope_tab_k<<<dim3((SEQN*32+255)/256), 256, 0, stream>>>(tab);
    split3_k<<<dim3((NX+255)/256), 256, 0, stream>>>(X,  NX, Xh, Xm, Xl);
    split3_k<<<dim3((NW+255)/256), 256, 0, stream>>>(Wq, NW, Wq3, Wq3+NW, Wq3+2*NW);
    split3_k<<<dim3((NW+255)/256), 256, 0, stream>>>(Wk, NW, Wk3, Wk3+NW, Wk3+2*NW);
    split3_k<<<dim3((NW+255)/256), 256, 0, stream>>>(Wv, NW, Wv3, Wv3+NW, Wv3+2*NW);
    split2_k<<<dim3((NW+255)/256), 256, 0, stream>>>(Wo, NW, Wo2, Wo2+NW);

    qkv_fused_gemm_k<<<dim3(576), 256, 0, stream>>>(
        Xh, Wq3, Wk3, Wv3, tab, q32, kh, km, vth, partial);

    reps_reduce_k<<<dim3(BATCH*NH*NB), 64, 0, stream>>>(partial, reps);
    select_topk_k<<<dim3(SEQN/128, BATCH*NH), 128, 0, stream>>>(q32, reps, selm);

    moba_attn_k<<<dim3(BATCH*NH*(SEQN/16)/2), 128, 0, stream>>>(
        q32, kh, km, vth, selm, aoh, aom);

    out_gemm_mfma_k<<<dim3(192), 256, 0, stream>>>(aoh, Wo2, out);
}

// Round 5
// 416.678 us; speedup vs baseline: 3.4059x; 1.0042x over previous
//
#include <hip/hip_runtime.h>
#include <math.h>

// MoBA attention, round 4: attention kernel restructured —
// 2-way union split per tile (intra-wg flash-decode merge), bias-trick
// masking (no per-element mask ops on non-current blocks), Q prescaled by
// 1/8 into fragments, trunc-split P packed as b64 LDS writes, causal-dead
// chunk skipping. Projections/selection unchanged from round 3 (passing).

#define HID   768
#define NH    12
#define DH    64
#define SEQN  2048
#define BATCH 2
#define NTOK  (BATCH*SEQN)   // 4096
#define NB    8
#define BLKSZ 256
#define NEG_INF (-__builtin_huge_valf())
#define POS_INF (__builtin_huge_valf())

typedef unsigned short u16;
typedef __bf16 v8bf __attribute__((ext_vector_type(8)));
typedef unsigned short v8us __attribute__((ext_vector_type(8)));
typedef float  v4f  __attribute__((ext_vector_type(4)));

union BF8 { v8us u; v8bf b; };

__device__ __forceinline__ u16 f2bf(float f) {
    unsigned u = __builtin_bit_cast(unsigned, f);
    u = (u + 0x7fffu + ((u >> 16) & 1u)) >> 16;      // RNE
    return (u16)u;
}
__device__ __forceinline__ float bf2f(u16 h) {
    unsigned u = ((unsigned)h) << 16;
    return __builtin_bit_cast(float, u);
}
__device__ __forceinline__ v8bf ldbf8(const u16* p) {
    return *reinterpret_cast<const v8bf*>(p);
}
__device__ __forceinline__ void g2lds16(const u16* g, u16* l) {
    __builtin_amdgcn_global_load_lds(
        (const __attribute__((address_space(1))) void*)g,
        (__attribute__((address_space(3))) void*)l, 16, 0, 0);
}

// ---------------------------------------------------------------------------
__global__ __launch_bounds__(256)
void rope_tab_k(float2* __restrict__ tab)
{
    int i = blockIdx.x * 256 + threadIdx.x;
    if (i >= SEQN * 32) return;
    int s = i >> 5, f = i & 31;
    double y  = exp((double)f * (log(10000.0) / 32.0));
    float  yf = (float)y;
    float  invf = 1.0f / yf;
    float  ang  = (float)s * invf;
    tab[i] = make_float2((float)sin((double)ang), (float)cos((double)ang));
}

// ---------------------------------------------------------------------------
__global__ __launch_bounds__(256)
void split3_k(const float* __restrict__ src, int n,
              u16* __restrict__ oh, u16* __restrict__ om, u16* __restrict__ ol)
{
    int i = blockIdx.x * 256 + threadIdx.x;
    if (i >= n) return;
    float x = src[i];
    u16 h = f2bf(x);
    float r1 = x - bf2f(h);
    u16 m = f2bf(r1);
    float r2 = r1 - bf2f(m);
    oh[i] = h; om[i] = m; ol[i] = f2bf(r2);
}

__global__ __launch_bounds__(256)
void split2_k(const float* __restrict__ src, int n,
              u16* __restrict__ oh, u16* __restrict__ om)
{
    int i = blockIdx.x * 256 + threadIdx.x;
    if (i >= n) return;
    float x = src[i];
    u16 h = f2bf(x);
    oh[i] = h; om[i] = f2bf(x - bf2f(h));
}

// ---------------------------------------------------------------------------
// 128x128 LDS-staged mainloop (round-3, unchanged).
__device__ __forceinline__
void gemm_mainloop(const u16* __restrict__ Abase, size_t aps,
                   const u16* __restrict__ Bbase,
                   int m0, int nb0, int nchunks,
                   u16* As, u16* Bs, v4f acc[4][4])
{
    const int asel_[6] = {0, 0, 1, 0, 1, 2};
    const int bsel_[6] = {0, 1, 0, 2, 1, 0};
    const int tid  = threadIdx.x;
    const int wave = tid >> 6, lane = tid & 63;
    const int col  = lane & 15, quad = lane >> 4;
    const int wr   = wave >> 1, wc = wave & 1;

    int ld_row[4], ld_gl[4];
    #pragma unroll
    for (int r = 0; r < 4; r++) {
        int g = r * 256 + tid;
        ld_row[r] = g >> 3;
        ld_gl[r]  = (g & 7) ^ (ld_row[r] & 7);
    }

    for (int c = 0; c < nchunks; c++) {
        const u16* Ap = Abase + (size_t)asel_[c] * aps;
        const u16* Bp = Bbase + (size_t)bsel_[c] * (HID * HID);
        for (int itc = 0; itc < HID / 64; itc++) {
            const int k0 = itc * 64;
            __syncthreads();
            #pragma unroll
            for (int r = 0; r < 4; r++) {
                g2lds16(Ap + (size_t)(m0 + ld_row[r]) * HID + k0 + ld_gl[r] * 8,
                        &As[(r * 256 + wave * 64) * 8]);
                g2lds16(Bp + (size_t)(nb0 + ld_row[r]) * HID + k0 + ld_gl[r] * 8,
                        &Bs[(r * 256 + wave * 64) * 8]);
            }
            __syncthreads();
            #pragma unroll
            for (int ks = 0; ks < 2; ks++) {
                v8bf af[4], bf_[4];
                #pragma unroll
                for (int mt = 0; mt < 4; mt++) {
                    const int row = wr * 64 + mt * 16 + col;
                    const int gph = (ks * 4 + quad) ^ (row & 7);
                    af[mt] = ldbf8(&As[row * 64 + gph * 8]);
                }
                #pragma unroll
                for (int nt = 0; nt < 4; nt++) {
                    const int row = wc * 64 + nt * 16 + col;
                    const int gph = (ks * 4 + quad) ^ (row & 7);
                    bf_[nt] = ldbf8(&Bs[row * 64 + gph * 8]);
                }
                #pragma unroll
                for (int mt = 0; mt < 4; mt++)
                    #pragma unroll
                    for (int nt = 0; nt < 4; nt++)
                        acc[mt][nt] = __builtin_amdgcn_mfma_f32_16x16x32_bf16(
                            af[mt], bf_[nt], acc[mt][nt], 0, 0, 0);
            }
        }
    }
    __syncthreads();
}

// ---------------------------------------------------------------------------
__global__ __launch_bounds__(256)
void qkv_fused_gemm_k(const u16* __restrict__ A3,
                      const u16* __restrict__ Wq3, const u16* __restrict__ Wk3,
                      const u16* __restrict__ Wv3, const float2* __restrict__ tab,
                      float* __restrict__ q32,
                      u16* __restrict__ kh, u16* __restrict__ km,
                      u16* __restrict__ vth, float* __restrict__ partial)
{
    __shared__ u16 As[128 * 64];
    __shared__ u16 Bs[128 * 64];
    __shared__ float psum[2][2][64];

    const int id    = blockIdx.x;
    const int xcd   = id & 7, loc = id >> 3;
    const int mtile = xcd * 4 + (loc & 3);
    const int ntile = loc >> 2;
    const int m0 = mtile * 128;
    const int n0 = ntile * 128;
    const int mat = n0 / HID;
    const int nb0 = n0 - mat * HID;
    const u16* Bbase = (mat == 0) ? Wq3 : (mat == 1) ? Wk3 : Wv3;
    const int nchunks = (mat == 2) ? 3 : 6;

    v4f acc[4][4] = {};
    gemm_mainloop(A3, (size_t)NTOK * HID, Bbase, m0, nb0, nchunks, As, Bs, acc);

    const int tid  = threadIdx.x;
    const int wave = tid >> 6, lane = tid & 63;
    const int col  = lane & 15, quad = lane >> 4;
    const int wr   = wave >> 1, wc = wave & 1;
    const int b    = m0 >> 11;
    const int h    = (nb0 + wc * 64) >> 6;
    const size_t bh = (size_t)b * NH + h;

    if (mat == 2) {
        #pragma unroll
        for (int nt = 0; nt < 4; nt++) {
            const int d = nt * 16 + col;
            #pragma unroll
            for (int mt = 0; mt < 4; mt++) {
                const int m = m0 + wr * 64 + mt * 16 + quad * 4;
                const int s = m & (SEQN - 1);
                ushort4 pk = make_ushort4(f2bf(acc[mt][nt][0]), f2bf(acc[mt][nt][1]),
                                          f2bf(acc[mt][nt][2]), f2bf(acc[mt][nt][3]));
                *(ushort4*)&vth[(bh * DH + d) * SEQN + s] = pk;
            }
        }
        return;
    }

    float vsum[4] = {0.f, 0.f, 0.f, 0.f};
    #pragma unroll
    for (int mt = 0; mt < 4; mt++) {
        #pragma unroll
        for (int nt = 0; nt < 4; nt++) {
            const int d = nt * 16 + col;
            #pragma unroll
            for (int r = 0; r < 4; r++) {
                const int m = m0 + wr * 64 + mt * 16 + quad * 4 + r;
                const int s = m & (SEQN - 1);
                const float part = acc[mt][nt ^ 2][r];
                const float2 sc = tab[(s << 5) + (d & 31)];
                const float val = (d < 32) ? acc[mt][nt][r] * sc.y - part * sc.x
                                           : acc[mt][nt][r] * sc.y + part * sc.x;
                const size_t idx = (bh * SEQN + s) * DH + d;
                if (mat == 0) {
                    q32[idx] = val;
                } else {
                    u16 hb = f2bf(val);
                    kh[idx] = hb;
                    km[idx] = f2bf(val - bf2f(hb));
                    vsum[nt] += val;
                }
            }
        }
    }
    if (mat == 1) {
        #pragma unroll
        for (int nt = 0; nt < 4; nt++) {
            float v = vsum[nt];
            v += __shfl_xor(v, 16);
            v += __shfl_xor(v, 32);
            if (quad == 0) psum[wr][wc][nt * 16 + col] = v;
        }
        __syncthreads();
        if (tid < 128) {
            const int wc2 = tid >> 6, d = tid & 63;
            const float s2 = psum[0][wc2][d] + psum[1][wc2][d];
            const int h2 = (nb0 + wc2 * 64) >> 6;
            const int nblk = (m0 & (SEQN - 1)) >> 8;
            const int half = (m0 >> 7) & 1;
            partial[((((size_t)b * NH + h2) * NB + nblk) * 2 + half) * 64 + d] = s2;
        }
    }
}

// ---------------------------------------------------------------------------
__global__ __launch_bounds__(256)
void out_gemm_mfma_k(const u16* __restrict__ A2, const u16* __restrict__ Wo2,
                     float* __restrict__ C)
{
    __shared__ u16 As[128 * 64];
    __shared__ u16 Bs[128 * 64];

    const int id    = blockIdx.x;
    const int xcd   = id & 7, loc = id >> 3;
    const int mtile = xcd * 4 + (loc & 3);
    const int ntile = loc >> 2;
    const int m0 = mtile * 128;
    const int n0 = ntile * 128;

    v4f acc[4][4] = {};
    gemm_mainloop(A2, (size_t)NTOK * HID, Wo2, m0, n0, 3, As, Bs, acc);

    const int tid  = threadIdx.x;
    const int wave = tid >> 6, lane = tid & 63;
    const int col  = lane & 15, quad = lane >> 4;
    const int wr   = wave >> 1, wc = wave & 1;

    #pragma unroll
    for (int mt = 0; mt < 4; mt++)
        #pragma unroll
        for (int nt = 0; nt < 4; nt++)
            #pragma unroll
            for (int r = 0; r < 4; r++) {
                const int m = m0 + wr * 64 + mt * 16 + quad * 4 + r;
                C[(size_t)m * HID + n0 + wc * 64 + nt * 16 + col] = acc[mt][nt][r];
            }
}

// ---------------------------------------------------------------------------
__global__ __launch_bounds__(64)
void reps_reduce_k(const float* __restrict__ partial, float* __restrict__ reps)
{
    const int bhn = blockIdx.x;
    const int d = threadIdx.x;
    const float* p = &partial[(size_t)bhn * 128 + d];
    double s = (double)p[0] + (double)p[64];
    reps[(size_t)bhn * 64 + d] = (float)(s * (1.0 / 256.0));
}

// ---------------------------------------------------------------------------
__global__ __launch_bounds__(128)
void select_topk_k(const float* __restrict__ qg, const float* __restrict__ reps,
                   unsigned* __restrict__ selm)
{
    __shared__ float rs[NB][DH];
    const int bh = blockIdx.y;
    const int tid = threadIdx.x;
    for (int idx = tid; idx < NB * DH; idx += 128)
        rs[idx >> 6][idx & 63] = reps[(size_t)bh * NB * DH + idx];
    __syncthreads();

    const int qq = blockIdx.x * 128 + tid;
    const float* qv = &qg[((size_t)bh * SEQN + qq) * DH];
    float qr[DH];
    #pragma unroll
    for (int c = 0; c < 16; c++) {
        float4 t = *(const float4*)&qv[c * 4];
        qr[c*4+0]=t.x; qr[c*4+1]=t.y; qr[c*4+2]=t.z; qr[c*4+3]=t.w;
    }
    const int cur = qq >> 8;
    double sc[NB];
    #pragma unroll
    for (int n = 0; n < NB; n++) {
        double ssum = 0.0;
        for (int d = 0; d < DH; d++) ssum += (double)qr[d] * (double)rs[n][d];
        sc[n] = ssum * 0.125;
    }
    for (int n = cur + 1; n < NB; n++) sc[n] = -1e300;
    sc[cur] = 1e300;
    unsigned mask = 0;
    for (int p = 0; p < 3; p++) {
        int bi = -1; double bv = 0.0;
        for (int n = 0; n < NB; n++) {
            if ((mask >> n) & 1) continue;
            if (bi < 0 || sc[n] > bv) { bi = n; bv = sc[n]; }
        }
        mask |= 1u << bi;
    }
    selm[(size_t)bh * SEQN + qq] = mask;
}

// ---------------------------------------------------------------------------
// MFMA flash attention, 2-way union split + intra-wg merge.
// wg = 128 thr = 2 waves, one 16-query tile; wave w handles union blocks
// {w, w+2, ...}; partial (m,l,O) merged via LDS (wave1 -> its plds half).
__global__ __launch_bounds__(128, 4)
void moba_attn_k(const float* __restrict__ q32,
                 const u16* __restrict__ kh, const u16* __restrict__ km,
                 const u16* __restrict__ vth, const unsigned* __restrict__ selm,
                 u16* __restrict__ aoh, u16* __restrict__ aom)
{
    __shared__ u16 plds[2][2][16][72];               // 9216 B; wave-private halves
    float* mrg = (float*)&plds[1][0][0][0];          // wave1 half: 1152 floats

    const int id   = blockIdx.x;
    const int xcd  = id & 7, loc = id >> 3;          // 384 wgs per XCD
    const int bh   = xcd * 3 + (loc >> 7);           // 3 bh per XCD (L2-local K/V)
    const int qw0  = (loc & 127) * 16;
    const int cur  = qw0 >> 8;
    const int tid  = threadIdx.x;
    const int wave = tid >> 6;
    const int lane = tid & 63;
    const int col  = lane & 15, quad = lane >> 4;
    const size_t bhS = (size_t)bh * SEQN;
    const int qpos = qw0 + col;

    const unsigned mymask = selm[bhS + qw0 + col];
    unsigned uni = mymask;
    #pragma unroll
    for (int off = 1; off < 16; off <<= 1) uni |= __shfl_xor(uni, off, 16);

    // enumerate union blocks
    int list[NB], cnt = 0;
    #pragma unroll
    for (int n = 0; n < NB; n++)
        if ((uni >> n) & 1) list[cnt++] = n;

    // Q fragments, prescaled by 1/8, hi/lo split in-register
    v8bf qh[2], ql[2];
    #pragma unroll
    for (int ks = 0; ks < 2; ks++) {
        const float* qp = &q32[(bhS + qw0 + col) * DH + ks * 32 + quad * 8];
        float4 f0 = *(const float4*)qp;
        float4 f1 = *(const float4*)(qp + 4);
        float qf[8] = {f0.x, f0.y, f0.z, f0.w, f1.x, f1.y, f1.z, f1.w};
        BF8 uh, ul;
        #pragma unroll
        for (int j = 0; j < 8; j++) {
            float s = qf[j] * 0.125f;
            u16 hb = f2bf(s);
            uh.u[j] = hb;
            ul.u[j] = f2bf(s - bf2f(hb));
        }
        qh[ks] = uh.b; ql[ks] = ul.b;
    }

    const v4f zero4 = {0.f, 0.f, 0.f, 0.f};
    v4f oacc[4] = {zero4, zero4, zero4, zero4};
    float m_i = NEG_INF, l_i = 0.f;
    const bool selq_any_lane_dummy = false; (void)selq_any_lane_dummy;

    for (int idx = wave; idx < cnt; idx += 2) {
        const int n = list[idx];
        const bool iscur = (n == cur);
        const float sel01inf = ((mymask >> n) & 1) ? 0.f : POS_INF; // bias add
        // chunks: skip fully-future chunks of the current block
        const int c2max = iscur ? ((qw0 + 15 - n * BLKSZ) >> 6) : 3;
        for (int c2 = 0; c2 <= c2max; c2++) {
            const int kb = n * BLKSZ + c2 * 64;
            const bool need_mask = iscur && (kb + 63 > qw0);

            // ---- S^T[64k x 16q], 6-MFMA split (scaled)
            v4f sf[4];
            #pragma unroll
            for (int mt = 0; mt < 4; mt++) {
                const size_t kbase = (bhS + kb + mt * 16 + col) * DH + quad * 8;
                v8bf ah0 = ldbf8(kh + kbase);
                v8bf ah1 = ldbf8(kh + kbase + 32);
                v8bf al0 = ldbf8(km + kbase);
                v8bf al1 = ldbf8(km + kbase + 32);
                v4f c = zero4;
                c = __builtin_amdgcn_mfma_f32_16x16x32_bf16(ah0, qh[0], c, 0,0,0);
                c = __builtin_amdgcn_mfma_f32_16x16x32_bf16(ah1, qh[1], c, 0,0,0);
                c = __builtin_amdgcn_mfma_f32_16x16x32_bf16(ah0, ql[0], c, 0,0,0);
                c = __builtin_amdgcn_mfma_f32_16x16x32_bf16(ah1, ql[1], c, 0,0,0);
                c = __builtin_amdgcn_mfma_f32_16x16x32_bf16(al0, qh[0], c, 0,0,0);
                c = __builtin_amdgcn_mfma_f32_16x16x32_bf16(al1, qh[1], c, 0,0,0);
                sf[mt] = c;
            }

            // ---- causal mask only on straddle chunks of cur block
            if (need_mask) {
                #pragma unroll
                for (int mt = 0; mt < 4; mt++)
                    #pragma unroll
                    for (int r = 0; r < 4; r++) {
                        const int kidx = kb + mt * 16 + quad * 4 + r;
                        sf[mt][r] = (kidx <= qpos) ? sf[mt][r] : NEG_INF;
                    }
            }

            // ---- row max (per query col, across quads)
            float rm = NEG_INF;
            #pragma unroll
            for (int mt = 0; mt < 4; mt++)
                #pragma unroll
                for (int r = 0; r < 4; r++) rm = fmaxf(rm, sf[mt][r]);
            rm = fmaxf(rm, __shfl_xor(rm, 16));
            rm = fmaxf(rm, __shfl_xor(rm, 32));
            rm = rm - sel01inf;                       // unselected -> -inf
            const float mnew  = fmaxf(m_i, rm);
            const float alpha = (m_i == NEG_INF) ? 0.f : __expf(m_i - mnew);
            const float bias  = ((mnew == NEG_INF) ? 0.f : mnew) + sel01inf;

            // ---- exp + trunc-split P, packed b64 LDS writes
            float lsum = 0.f;
            #pragma unroll
            for (int mt = 0; mt < 4; mt++) {
                ushort4 hv, lv;
                #pragma unroll
                for (int r = 0; r < 4; r++) {
                    float p = __expf(sf[mt][r] - bias);   // 0 if masked/unsel
                    lsum += p;
                    unsigned u = __builtin_bit_cast(unsigned, p);
                    unsigned hf = u & 0xFFFF0000u;
                    float resid = p - __builtin_bit_cast(float, hf);
                    u16 hu = (u16)(u >> 16);
                    u16 lu = f2bf(resid);
                    if (r == 0) { hv.x = hu; lv.x = lu; }
                    else if (r == 1) { hv.y = hu; lv.y = lu; }
                    else if (r == 2) { hv.z = hu; lv.z = lu; }
                    else { hv.w = hu; lv.w = lu; }
                }
                *(ushort4*)&plds[wave][0][col][mt * 16 + quad * 4] = hv;
                *(ushort4*)&plds[wave][1][col][mt * 16 + quad * 4] = lv;
            }
            lsum += __shfl_xor(lsum, 16);
            lsum += __shfl_xor(lsum, 32);
            l_i = l_i * alpha + lsum;
            m_i = mnew;

            // ---- rescale O rows
            float ar[4];
            #pragma unroll
            for (int r = 0; r < 4; r++) ar[r] = __shfl(alpha, quad * 4 + r, 16);
            #pragma unroll
            for (int nt = 0; nt < 4; nt++)
                #pragma unroll
                for (int r = 0; r < 4; r++) oacc[nt][r] *= ar[r];

            __threadfence_block();

            // ---- O += (Ph + Pl) * Vh
            #pragma unroll
            for (int ks2 = 0; ks2 < 2; ks2++) {
                v8bf ph = ldbf8(&plds[wave][0][col][ks2 * 32 + quad * 8]);
                v8bf pl = ldbf8(&plds[wave][1][col][ks2 * 32 + quad * 8]);
                #pragma unroll
                for (int nt = 0; nt < 4; nt++) {
                    const size_t vb = ((size_t)bh * DH + nt * 16 + col) * SEQN
                                    + kb + ks2 * 32 + quad * 8;
                    v8bf vh = ldbf8(vth + vb);
                    oacc[nt] = __builtin_amdgcn_mfma_f32_16x16x32_bf16(ph, vh, oacc[nt], 0,0,0);
                    oacc[nt] = __builtin_amdgcn_mfma_f32_16x16x32_bf16(pl, vh, oacc[nt], 0,0,0);
                }
            }
            __threadfence_block();   // protect plds before next-chunk overwrite
        }
    }

    // ---- merge wave1 partials into wave0 via LDS (wave1's plds half)
    __syncthreads();
    if (wave == 1) {
        mrg[lane] = m_i;
        mrg[64 + lane] = l_i;
        #pragma unroll
        for (int nt = 0; nt < 4; nt++)
            #pragma unroll
            for (int r = 0; r < 4; r++)
                mrg[128 + lane * 16 + nt * 4 + r] = oacc[nt][r];
    }
    __syncthreads();
    if (wave == 1) return;

    {
        const float m1 = mrg[lane];
        const float l1 = mrg[64 + lane];
        const float mnew = fmaxf(m_i, m1);
        const float a0 = (m_i == NEG_INF) ? 0.f : __expf(m_i - mnew);
        const float a1 = (m1  == NEG_INF) ? 0.f : __expf(m1 - mnew);
        const float l = l_i * a0 + l1 * a1;
        float a0r[4], a1r[4], ir[4];
        const float invl = 1.f / l;
        #pragma unroll
        for (int r = 0; r < 4; r++) {
            a0r[r] = __shfl(a0, quad * 4 + r, 16);
            a1r[r] = __shfl(a1, quad * 4 + r, 16);
            ir[r]  = __shfl(invl, quad * 4 + r, 16);
        }
        const int b = bh / NH, h = bh % NH;
        #pragma unroll
        for (int nt = 0; nt < 4; nt++)
            #pragma unroll
            for (int r = 0; r < 4; r++) {
                const float o1 = mrg[128 + (quad * 4 + r) * 16 +  /*lane row*/ 0];
                // careful: O element for (query=quad*4+r? ) -- see below
                (void)o1;
            }
        // Correct indexing: wave1 stored per ITS lane (same mapping as ours):
        // element (nt,r) of lane L lives at mrg[128 + L*16 + nt*4 + r].
        // Our lane needs the SAME (nt,r) of the SAME lane index -> direct.
        #pragma unroll
        for (int nt = 0; nt < 4; nt++)
            #pragma unroll
            for (int r = 0; r < 4; r++) {
                const float o1 = mrg[128 + lane * 16 + nt * 4 + r];
                const float val = (oacc[nt][r] * a0r[r] + o1 * a1r[r]) * ir[r];
                const int qi = qw0 + quad * 4 + r;
                const size_t idx = ((size_t)b * SEQN + qi) * HID + h * DH + nt * 16 + col;
                u16 hb = f2bf(val);
                aoh[idx] = hb;
                aom[idx] = f2bf(val - bf2f(hb));
            }
    }
}

// ---------------------------------------------------------------------------
extern "C" void kernel_launch(void* const* d_in, const int* in_sizes, int n_in,
                              void* d_out, int out_size, void* d_ws, size_t ws_size,
                              hipStream_t stream)
{
    const float* X  = (const float*)d_in[0];
    const float* Wq = (const float*)d_in[1];
    const float* Wk = (const float*)d_in[2];
    const float* Wv = (const float*)d_in[3];
    const float* Wo = (const float*)d_in[4];
    float* out = (float*)d_out;

    char* p = (char*)d_ws;
    float* q32 = (float*)p;                p += (size_t)NTOK*HID*4;
    u16* kh  = (u16*)p;                    p += (size_t)NTOK*HID*2;
    u16* km  = (u16*)p;                    p += (size_t)NTOK*HID*2;
    u16* vth = (u16*)p;                    p += (size_t)NTOK*HID*2;
    u16* Xh  = (u16*)p;                    p += (size_t)NTOK*HID*2;   // aoh alias
    u16* Xm  = (u16*)p;                    p += (size_t)NTOK*HID*2;   // aom alias
    u16* Xl  = (u16*)p;                    p += (size_t)NTOK*HID*2;
    u16* Wq3 = (u16*)p;                    p += (size_t)HID*HID*2*3;
    u16* Wk3 = (u16*)p;                    p += (size_t)HID*HID*2*3;
    u16* Wv3 = (u16*)p;                    p += (size_t)HID*HID*2*3;
    u16* Wo2 = (u16*)p;                    p += (size_t)HID*HID*2*2;
    float* partial = (float*)p;            p += (size_t)BATCH*NH*NB*2*64*4;
    float* reps    = (float*)p;            p += (size_t)BATCH*NH*NB*DH*4;
    unsigned* selm = (unsigned*)p;         p += (size_t)BATCH*NH*SEQN*4;
    float2* tab    = (float2*)p;           p += (size_t)SEQN*32*8;
    u16* aoh = Xh;
    u16* aom = Xm;

    const int NX = NTOK*HID;
    const int NW = HID*HID;

    rope_tab_k<<<dim3((SEQN*32+255)/256), 256, 0, stream>>>(tab);
    split3_k<<<dim3((NX+255)/256), 256, 0, stream>>>(X,  NX, Xh, Xm, Xl);
    split3_k<<<dim3((NW+255)/256), 256, 0, stream>>>(Wq, NW, Wq3, Wq3+NW, Wq3+2*NW);
    split3_k<<<dim3((NW+255)/256), 256, 0, stream>>>(Wk, NW, Wk3, Wk3+NW, Wk3+2*NW);
    split3_k<<<dim3((NW+255)/256), 256, 0, stream>>>(Wv, NW, Wv3, Wv3+NW, Wv3+2*NW);
    split2_k<<<dim3((NW+255)/256), 256, 0, stream>>>(Wo, NW, Wo2, Wo2+NW);

    qkv_fused_gemm_k<<<dim3(576), 256, 0, stream>>>(
        Xh, Wq3, Wk3, Wv3, tab, q32, kh, km, vth, partial);

    reps_reduce_k<<<dim3(BATCH*NH*NB), 64, 0, stream>>>(partial, reps);
    select_topk_k<<<dim3(SEQN/128, BATCH*NH), 128, 0, stream>>>(q32, reps, selm);

    moba_attn_k<<<dim3(BATCH*NH*(SEQN/16)), 128, 0, stream>>>(
        q32, kh, km, vth, selm, aoh, aom);

    out_gemm_mfma_k<<<dim3(192), 256, 0, stream>>>(aoh, Wo2, out);
}

// Round 6
// 318.185 us; speedup vs baseline: 4.4601x; 1.3095x over previous
//
#include <hip/hip_runtime.h>
#include <math.h>

// MoBA attention, round 5: attention rewritten m97-style —
// 4-wave wg per 64-query tile, K/V chunks staged via global_load_lds into
// double-buffered swizzled LDS shared by all waves; wg-uniform chunk list
// (no divergence); bias-trick masking kept. Weight splits fused to 1 launch.

#define HID   768
#define NH    12
#define DH    64
#define SEQN  2048
#define BATCH 2
#define NTOK  (BATCH*SEQN)   // 4096
#define NB    8
#define BLKSZ 256
#define NEG_INF (-__builtin_huge_valf())
#define POS_INF (__builtin_huge_valf())

typedef unsigned short u16;
typedef __bf16 v8bf __attribute__((ext_vector_type(8)));
typedef unsigned short v8us __attribute__((ext_vector_type(8)));
typedef float  v4f  __attribute__((ext_vector_type(4)));

union BF8 { v8us u; v8bf b; };

__device__ __forceinline__ u16 f2bf(float f) {
    unsigned u = __builtin_bit_cast(unsigned, f);
    u = (u + 0x7fffu + ((u >> 16) & 1u)) >> 16;      // RNE
    return (u16)u;
}
__device__ __forceinline__ float bf2f(u16 h) {
    unsigned u = ((unsigned)h) << 16;
    return __builtin_bit_cast(float, u);
}
__device__ __forceinline__ v8bf ldbf8(const u16* p) {
    return *reinterpret_cast<const v8bf*>(p);
}
__device__ __forceinline__ void g2lds16(const u16* g, u16* l) {
    __builtin_amdgcn_global_load_lds(
        (const __attribute__((address_space(1))) void*)g,
        (__attribute__((address_space(3))) void*)l, 16, 0, 0);
}

// ---------------------------------------------------------------------------
__global__ __launch_bounds__(256)
void rope_tab_k(float2* __restrict__ tab)
{
    int i = blockIdx.x * 256 + threadIdx.x;
    if (i >= SEQN * 32) return;
    int s = i >> 5, f = i & 31;
    double y  = exp((double)f * (log(10000.0) / 32.0));
    float  yf = (float)y;
    float  invf = 1.0f / yf;
    float  ang  = (float)s * invf;
    tab[i] = make_float2((float)sin((double)ang), (float)cos((double)ang));
}

// ---------------------------------------------------------------------------
__global__ __launch_bounds__(256)
void split3_k(const float* __restrict__ src, int n,
              u16* __restrict__ oh, u16* __restrict__ om, u16* __restrict__ ol)
{
    int i = blockIdx.x * 256 + threadIdx.x;
    if (i >= n) return;
    float x = src[i];
    u16 h = f2bf(x);
    float r1 = x - bf2f(h);
    u16 m = f2bf(r1);
    float r2 = r1 - bf2f(m);
    oh[i] = h; om[i] = m; ol[i] = f2bf(r2);
}

// All four weight matrices in one launch: z=0..2 3-way split, z=3 2-way.
__global__ __launch_bounds__(256)
void wsplit_k(const float* __restrict__ Wq, const float* __restrict__ Wk,
              const float* __restrict__ Wv, const float* __restrict__ Wo,
              u16* __restrict__ Wq3, u16* __restrict__ Wk3,
              u16* __restrict__ Wv3, u16* __restrict__ Wo2)
{
    const int NW = HID * HID;
    const int z = blockIdx.y;
    const int i = blockIdx.x * 256 + threadIdx.x;
    const float* src = (z == 0) ? Wq : (z == 1) ? Wk : (z == 2) ? Wv : Wo;
    float x = src[i];
    u16 h = f2bf(x);
    float r1 = x - bf2f(h);
    if (z == 3) {
        Wo2[i] = h; Wo2[i + NW] = f2bf(r1);
        return;
    }
    u16* dst = (z == 0) ? Wq3 : (z == 1) ? Wk3 : Wv3;
    u16 m = f2bf(r1);
    dst[i] = h; dst[i + NW] = m; dst[i + 2 * NW] = f2bf(r1 - bf2f(m));
}

// ---------------------------------------------------------------------------
// 128x128 LDS-staged mainloop (round-3, unchanged).
__device__ __forceinline__
void gemm_mainloop(const u16* __restrict__ Abase, size_t aps,
                   const u16* __restrict__ Bbase,
                   int m0, int nb0, int nchunks,
                   u16* As, u16* Bs, v4f acc[4][4])
{
    const int asel_[6] = {0, 0, 1, 0, 1, 2};
    const int bsel_[6] = {0, 1, 0, 2, 1, 0};
    const int tid  = threadIdx.x;
    const int wave = tid >> 6, lane = tid & 63;
    const int col  = lane & 15, quad = lane >> 4;
    const int wr   = wave >> 1, wc = wave & 1;

    int ld_row[4], ld_gl[4];
    #pragma unroll
    for (int r = 0; r < 4; r++) {
        int g = r * 256 + tid;
        ld_row[r] = g >> 3;
        ld_gl[r]  = (g & 7) ^ (ld_row[r] & 7);
    }

    for (int c = 0; c < nchunks; c++) {
        const u16* Ap = Abase + (size_t)asel_[c] * aps;
        const u16* Bp = Bbase + (size_t)bsel_[c] * (HID * HID);
        for (int itc = 0; itc < HID / 64; itc++) {
            const int k0 = itc * 64;
            __syncthreads();
            #pragma unroll
            for (int r = 0; r < 4; r++) {
                g2lds16(Ap + (size_t)(m0 + ld_row[r]) * HID + k0 + ld_gl[r] * 8,
                        &As[(r * 256 + wave * 64) * 8]);
                g2lds16(Bp + (size_t)(nb0 + ld_row[r]) * HID + k0 + ld_gl[r] * 8,
                        &Bs[(r * 256 + wave * 64) * 8]);
            }
            __syncthreads();
            #pragma unroll
            for (int ks = 0; ks < 2; ks++) {
                v8bf af[4], bf_[4];
                #pragma unroll
                for (int mt = 0; mt < 4; mt++) {
                    const int row = wr * 64 + mt * 16 + col;
                    const int gph = (ks * 4 + quad) ^ (row & 7);
                    af[mt] = ldbf8(&As[row * 64 + gph * 8]);
                }
                #pragma unroll
                for (int nt = 0; nt < 4; nt++) {
                    const int row = wc * 64 + nt * 16 + col;
                    const int gph = (ks * 4 + quad) ^ (row & 7);
                    bf_[nt] = ldbf8(&Bs[row * 64 + gph * 8]);
                }
                #pragma unroll
                for (int mt = 0; mt < 4; mt++)
                    #pragma unroll
                    for (int nt = 0; nt < 4; nt++)
                        acc[mt][nt] = __builtin_amdgcn_mfma_f32_16x16x32_bf16(
                            af[mt], bf_[nt], acc[mt][nt], 0, 0, 0);
            }
        }
    }
    __syncthreads();
}

// ---------------------------------------------------------------------------
__global__ __launch_bounds__(256)
void qkv_fused_gemm_k(const u16* __restrict__ A3,
                      const u16* __restrict__ Wq3, const u16* __restrict__ Wk3,
                      const u16* __restrict__ Wv3, const float2* __restrict__ tab,
                      float* __restrict__ q32,
                      u16* __restrict__ kh, u16* __restrict__ km,
                      u16* __restrict__ vth, float* __restrict__ partial)
{
    __shared__ u16 As[128 * 64];
    __shared__ u16 Bs[128 * 64];
    __shared__ float psum[2][2][64];

    const int id    = blockIdx.x;
    const int xcd   = id & 7, loc = id >> 3;
    const int mtile = xcd * 4 + (loc & 3);
    const int ntile = loc >> 2;
    const int m0 = mtile * 128;
    const int n0 = ntile * 128;
    const int mat = n0 / HID;
    const int nb0 = n0 - mat * HID;
    const u16* Bbase = (mat == 0) ? Wq3 : (mat == 1) ? Wk3 : Wv3;
    const int nchunks = (mat == 2) ? 3 : 6;

    v4f acc[4][4] = {};
    gemm_mainloop(A3, (size_t)NTOK * HID, Bbase, m0, nb0, nchunks, As, Bs, acc);

    const int tid  = threadIdx.x;
    const int wave = tid >> 6, lane = tid & 63;
    const int col  = lane & 15, quad = lane >> 4;
    const int wr   = wave >> 1, wc = wave & 1;
    const int b    = m0 >> 11;
    const int h    = (nb0 + wc * 64) >> 6;
    const size_t bh = (size_t)b * NH + h;

    if (mat == 2) {
        #pragma unroll
        for (int nt = 0; nt < 4; nt++) {
            const int d = nt * 16 + col;
            #pragma unroll
            for (int mt = 0; mt < 4; mt++) {
                const int m = m0 + wr * 64 + mt * 16 + quad * 4;
                const int s = m & (SEQN - 1);
                ushort4 pk = make_ushort4(f2bf(acc[mt][nt][0]), f2bf(acc[mt][nt][1]),
                                          f2bf(acc[mt][nt][2]), f2bf(acc[mt][nt][3]));
                *(ushort4*)&vth[(bh * DH + d) * SEQN + s] = pk;
            }
        }
        return;
    }

    float vsum[4] = {0.f, 0.f, 0.f, 0.f};
    #pragma unroll
    for (int mt = 0; mt < 4; mt++) {
        #pragma unroll
        for (int nt = 0; nt < 4; nt++) {
            const int d = nt * 16 + col;
            #pragma unroll
            for (int r = 0; r < 4; r++) {
                const int m = m0 + wr * 64 + mt * 16 + quad * 4 + r;
                const int s = m & (SEQN - 1);
                const float part = acc[mt][nt ^ 2][r];
                const float2 sc = tab[(s << 5) + (d & 31)];
                const float val = (d < 32) ? acc[mt][nt][r] * sc.y - part * sc.x
                                           : acc[mt][nt][r] * sc.y + part * sc.x;
                const size_t idx = (bh * SEQN + s) * DH + d;
                if (mat == 0) {
                    q32[idx] = val;
                } else {
                    u16 hb = f2bf(val);
                    kh[idx] = hb;
                    km[idx] = f2bf(val - bf2f(hb));
                    vsum[nt] += val;
                }
            }
        }
    }
    if (mat == 1) {
        #pragma unroll
        for (int nt = 0; nt < 4; nt++) {
            float v = vsum[nt];
            v += __shfl_xor(v, 16);
            v += __shfl_xor(v, 32);
            if (quad == 0) psum[wr][wc][nt * 16 + col] = v;
        }
        __syncthreads();
        if (tid < 128) {
            const int wc2 = tid >> 6, d = tid & 63;
            const float s2 = psum[0][wc2][d] + psum[1][wc2][d];
            const int h2 = (nb0 + wc2 * 64) >> 6;
            const int nblk = (m0 & (SEQN - 1)) >> 8;
            const int half = (m0 >> 7) & 1;
            partial[((((size_t)b * NH + h2) * NB + nblk) * 2 + half) * 64 + d] = s2;
        }
    }
}

// ---------------------------------------------------------------------------
__global__ __launch_bounds__(256)
void out_gemm_mfma_k(const u16* __restrict__ A2, const u16* __restrict__ Wo2,
                     float* __restrict__ C)
{
    __shared__ u16 As[128 * 64];
    __shared__ u16 Bs[128 * 64];

    const int id    = blockIdx.x;
    const int xcd   = id & 7, loc = id >> 3;
    const int mtile = xcd * 4 + (loc & 3);
    const int ntile = loc >> 2;
    const int m0 = mtile * 128;
    const int n0 = ntile * 128;

    v4f acc[4][4] = {};
    gemm_mainloop(A2, (size_t)NTOK * HID, Wo2, m0, n0, 3, As, Bs, acc);

    const int tid  = threadIdx.x;
    const int wave = tid >> 6, lane = tid & 63;
    const int col  = lane & 15, quad = lane >> 4;
    const int wr   = wave >> 1, wc = wave & 1;

    #pragma unroll
    for (int mt = 0; mt < 4; mt++)
        #pragma unroll
        for (int nt = 0; nt < 4; nt++)
            #pragma unroll
            for (int r = 0; r < 4; r++) {
                const int m = m0 + wr * 64 + mt * 16 + quad * 4 + r;
                C[(size_t)m * HID + n0 + wc * 64 + nt * 16 + col] = acc[mt][nt][r];
            }
}

// ---------------------------------------------------------------------------
__global__ __launch_bounds__(64)
void reps_reduce_k(const float* __restrict__ partial, float* __restrict__ reps)
{
    const int bhn = blockIdx.x;
    const int d = threadIdx.x;
    const float* p = &partial[(size_t)bhn * 128 + d];
    double s = (double)p[0] + (double)p[64];
    reps[(size_t)bhn * 64 + d] = (float)(s * (1.0 / 256.0));
}

// ---------------------------------------------------------------------------
__global__ __launch_bounds__(128)
void select_topk_k(const float* __restrict__ qg, const float* __restrict__ reps,
                   unsigned* __restrict__ selm)
{
    __shared__ float rs[NB][DH];
    const int bh = blockIdx.y;
    const int tid = threadIdx.x;
    for (int idx = tid; idx < NB * DH; idx += 128)
        rs[idx >> 6][idx & 63] = reps[(size_t)bh * NB * DH + idx];
    __syncthreads();

    const int qq = blockIdx.x * 128 + tid;
    const float* qv = &qg[((size_t)bh * SEQN + qq) * DH];
    float qr[DH];
    #pragma unroll
    for (int c = 0; c < 16; c++) {
        float4 t = *(const float4*)&qv[c * 4];
        qr[c*4+0]=t.x; qr[c*4+1]=t.y; qr[c*4+2]=t.z; qr[c*4+3]=t.w;
    }
    const int cur = qq >> 8;
    double sc[NB];
    #pragma unroll
    for (int n = 0; n < NB; n++) {
        double ssum = 0.0;
        for (int d = 0; d < DH; d++) ssum += (double)qr[d] * (double)rs[n][d];
        sc[n] = ssum * 0.125;
    }
    for (int n = cur + 1; n < NB; n++) sc[n] = -1e300;
    sc[cur] = 1e300;
    unsigned mask = 0;
    for (int p = 0; p < 3; p++) {
        int bi = -1; double bv = 0.0;
        for (int n = 0; n < NB; n++) {
            if ((mask >> n) & 1) continue;
            if (bi < 0 || sc[n] > bv) { bi = n; bv = sc[n]; }
        }
        mask |= 1u << bi;
    }
    selm[(size_t)bh * SEQN + qq] = mask;
}

// ---------------------------------------------------------------------------
// MFMA flash attention, LDS-staged K/V shared by 4 waves.
// wg = 256 thr = one 64-query tile of one bh; wave w owns queries
// [q0+16w, q0+16w+16). wg-uniform chunk list from the 64-query union;
// double-buffered global_load_lds staging, one barrier per chunk.
__global__ __launch_bounds__(256, 2)
void moba_attn_k(const float* __restrict__ q32,
                 const u16* __restrict__ kh, const u16* __restrict__ km,
                 const u16* __restrict__ vth, const unsigned* __restrict__ selm,
                 u16* __restrict__ aoh, u16* __restrict__ aom)
{
    __shared__ u16 kbuf[2][2][64 * 64];   // [buf][hi/lo] keys x d (swizzled)
    __shared__ u16 vbuf[2][64 * 64];      // [buf] d x keys (swizzled)
    __shared__ u16 plds[4][2][16][72];    // per-wave P hi/lo
    __shared__ unsigned s_uni;

    const int id  = blockIdx.x;                 // 768
    const int xcd = id & 7, loc = id >> 3;      // 96 per XCD
    const int bh  = xcd * 3 + (loc >> 5);       // 3 bh per XCD (L2-local K/V)
    const int q0  = (loc & 31) * 64;
    const int cur = q0 >> 8;
    const int tid = threadIdx.x;
    const int wave = tid >> 6, lane = tid & 63;
    const int col = lane & 15, quad = lane >> 4;
    const int qw0 = q0 + wave * 16;
    const int qpos = qw0 + col;
    const size_t bhS = (size_t)bh * SEQN;

    if (tid == 0) s_uni = 0;
    __syncthreads();
    const unsigned mymask = selm[bhS + qw0 + col];
    unsigned uw = mymask;
    #pragma unroll
    for (int off = 1; off < 16; off <<= 1) uw |= __shfl_xor(uw, off);
    if (lane == 0) atomicOr(&s_uni, uw);

    // Q fragments, prescaled by 1/8, hi/lo split in-register
    v8bf qh[2], ql[2];
    #pragma unroll
    for (int ks = 0; ks < 2; ks++) {
        const float* qp = &q32[(bhS + qw0 + col) * DH + ks * 32 + quad * 8];
        float4 f0 = *(const float4*)qp;
        float4 f1 = *(const float4*)(qp + 4);
        float qf[8] = {f0.x, f0.y, f0.z, f0.w, f1.x, f1.y, f1.z, f1.w};
        BF8 uh, ul;
        #pragma unroll
        for (int j = 0; j < 8; j++) {
            float s = qf[j] * 0.125f;
            u16 hb = f2bf(s);
            uh.u[j] = hb;
            ul.u[j] = f2bf(s - bf2f(hb));
        }
        qh[ks] = uh.b; ql[ks] = ul.b;
    }
    __syncthreads();
    const unsigned uni = s_uni;

    // wg-uniform chunk list
    int lst_n[4 * NB], lst_c[4 * NB], T = 0;
    #pragma unroll
    for (int n = 0; n < NB; n++) {
        if (!((uni >> n) & 1)) continue;
        const int c2max = (n == cur) ? ((q0 + 63 - n * BLKSZ) >> 6) : 3;
        for (int c2 = 0; c2 <= c2max; c2++) { lst_n[T] = n; lst_c[T] = c2; T++; }
    }

    // staging lambda: chunk t -> buffer t&1
    const int sg_row0 = tid >> 3;                       // granule row (g=tid)
    const int sg_gl0  = (tid & 7) ^ (sg_row0 & 7);
    const int sg_row1 = (256 + tid) >> 3;
    const int sg_gl1  = ((256 + tid) & 7) ^ (sg_row1 & 7);
    auto stage = [&](int t) {
        const int kb = lst_n[t] * BLKSZ + lst_c[t] * 64;
        u16* kb0 = (u16*)kbuf[t & 1][0];
        u16* kb1 = (u16*)kbuf[t & 1][1];
        u16* vb  = (u16*)vbuf[t & 1];
        const size_t ks0 = (bhS + kb + sg_row0) * DH + sg_gl0 * 8;
        const size_t ks1 = (bhS + kb + sg_row1) * DH + sg_gl1 * 8;
        const size_t vs0 = ((size_t)bh * DH + sg_row0) * SEQN + kb + sg_gl0 * 8;
        const size_t vs1 = ((size_t)bh * DH + sg_row1) * SEQN + kb + sg_gl1 * 8;
        g2lds16(kh + ks0,  kb0 + (wave * 64) * 8);
        g2lds16(kh + ks1,  kb0 + (256 + wave * 64) * 8);
        g2lds16(km + ks0,  kb1 + (wave * 64) * 8);
        g2lds16(km + ks1,  kb1 + (256 + wave * 64) * 8);
        g2lds16(vth + vs0, vb  + (wave * 64) * 8);
        g2lds16(vth + vs1, vb  + (256 + wave * 64) * 8);
    };

    const v4f zero4 = {0.f, 0.f, 0.f, 0.f};
    v4f oacc[4] = {zero4, zero4, zero4, zero4};
    float m_i = NEG_INF, l_i = 0.f;

    stage(0);
    for (int t = 0; t < T; t++) {
        __syncthreads();                 // buf[t&1] staged; prev reads done
        if (t + 1 < T) stage(t + 1);

        const int n = lst_n[t];
        const int kb = n * BLKSZ + lst_c[t] * 64;
        const bool iscur = (n == cur);
        const float sel01inf = ((mymask >> n) & 1) ? 0.f : POS_INF;
        const bool need_mask = iscur && (kb + 63 > qw0);
        const u16* kb0 = (const u16*)kbuf[t & 1][0];
        const u16* kb1 = (const u16*)kbuf[t & 1][1];
        const u16* vb  = (const u16*)vbuf[t & 1];

        // ---- S^T[64k x 16q], 6-MFMA split, K frags from LDS
        v4f sf[4];
        #pragma unroll
        for (int mt = 0; mt < 4; mt++) {
            const int row = mt * 16 + col;
            const int r7 = row & 7;
            v8bf ah0 = ldbf8(&kb0[(row * 8 + (quad ^ r7)) * 8]);
            v8bf ah1 = ldbf8(&kb0[(row * 8 + ((4 + quad) ^ r7)) * 8]);
            v8bf al0 = ldbf8(&kb1[(row * 8 + (quad ^ r7)) * 8]);
            v8bf al1 = ldbf8(&kb1[(row * 8 + ((4 + quad) ^ r7)) * 8]);
            v4f c = zero4;
            c = __builtin_amdgcn_mfma_f32_16x16x32_bf16(ah0, qh[0], c, 0,0,0);
            c = __builtin_amdgcn_mfma_f32_16x16x32_bf16(ah1, qh[1], c, 0,0,0);
            c = __builtin_amdgcn_mfma_f32_16x16x32_bf16(ah0, ql[0], c, 0,0,0);
            c = __builtin_amdgcn_mfma_f32_16x16x32_bf16(ah1, ql[1], c, 0,0,0);
            c = __builtin_amdgcn_mfma_f32_16x16x32_bf16(al0, qh[0], c, 0,0,0);
            c = __builtin_amdgcn_mfma_f32_16x16x32_bf16(al1, qh[1], c, 0,0,0);
            sf[mt] = c;
        }

        if (need_mask) {
            #pragma unroll
            for (int mt = 0; mt < 4; mt++)
                #pragma unroll
                for (int r = 0; r < 4; r++) {
                    const int kidx = kb + mt * 16 + quad * 4 + r;
                    sf[mt][r] = (kidx <= qpos) ? sf[mt][r] : NEG_INF;
                }
        }

        float rm = NEG_INF;
        #pragma unroll
        for (int mt = 0; mt < 4; mt++)
            #pragma unroll
            for (int r = 0; r < 4; r++) rm = fmaxf(rm, sf[mt][r]);
        rm = fmaxf(rm, __shfl_xor(rm, 16));
        rm = fmaxf(rm, __shfl_xor(rm, 32));
        rm = rm - sel01inf;
        const float mnew  = fmaxf(m_i, rm);
        const float alpha = (m_i == NEG_INF) ? 0.f : __expf(m_i - mnew);
        const float bias  = ((mnew == NEG_INF) ? 0.f : mnew) + sel01inf;

        float lsum = 0.f;
        #pragma unroll
        for (int mt = 0; mt < 4; mt++) {
            ushort4 hv, lv;
            #pragma unroll
            for (int r = 0; r < 4; r++) {
                float p = __expf(sf[mt][r] - bias);
                lsum += p;
                unsigned u = __builtin_bit_cast(unsigned, p);
                unsigned hf = u & 0xFFFF0000u;
                float resid = p - __builtin_bit_cast(float, hf);
                u16 hu = (u16)(u >> 16);
                u16 lu = f2bf(resid);
                if (r == 0) { hv.x = hu; lv.x = lu; }
                else if (r == 1) { hv.y = hu; lv.y = lu; }
                else if (r == 2) { hv.z = hu; lv.z = lu; }
                else { hv.w = hu; lv.w = lu; }
            }
            *(ushort4*)&plds[wave][0][col][mt * 16 + quad * 4] = hv;
            *(ushort4*)&plds[wave][1][col][mt * 16 + quad * 4] = lv;
        }
        lsum += __shfl_xor(lsum, 16);
        lsum += __shfl_xor(lsum, 32);
        l_i = l_i * alpha + lsum;
        m_i = mnew;

        float ar[4];
        #pragma unroll
        for (int r = 0; r < 4; r++) ar[r] = __shfl(alpha, quad * 4 + r, 16);
        #pragma unroll
        for (int nt = 0; nt < 4; nt++)
            #pragma unroll
            for (int r = 0; r < 4; r++) oacc[nt][r] *= ar[r];

        __threadfence_block();

        // ---- O += (Ph + Pl) * Vh, V frags from LDS
        #pragma unroll
        for (int ks2 = 0; ks2 < 2; ks2++) {
            v8bf ph = ldbf8(&plds[wave][0][col][ks2 * 32 + quad * 8]);
            v8bf pl = ldbf8(&plds[wave][1][col][ks2 * 32 + quad * 8]);
            #pragma unroll
            for (int nt = 0; nt < 4; nt++) {
                const int row = nt * 16 + col;
                const int g = (ks2 * 4 + quad) ^ (row & 7);
                v8bf vh = ldbf8(&vb[(row * 8 + g) * 8]);
                oacc[nt] = __builtin_amdgcn_mfma_f32_16x16x32_bf16(ph, vh, oacc[nt], 0,0,0);
                oacc[nt] = __builtin_amdgcn_mfma_f32_16x16x32_bf16(pl, vh, oacc[nt], 0,0,0);
            }
        }
    }

    // ---- epilogue: normalize rows, 2-way bf16 split store
    const int b = bh / NH, h = bh % NH;
    const float invl = 1.f / l_i;
    float ir[4];
    #pragma unroll
    for (int r = 0; r < 4; r++) ir[r] = __shfl(invl, quad * 4 + r, 16);
    #pragma unroll
    for (int nt = 0; nt < 4; nt++)
        #pragma unroll
        for (int r = 0; r < 4; r++) {
            const int qi = qw0 + quad * 4 + r;
            const size_t idx = ((size_t)b * SEQN + qi) * HID + h * DH + nt * 16 + col;
            float val = oacc[nt][r] * ir[r];
            u16 hb = f2bf(val);
            aoh[idx] = hb;
            aom[idx] = f2bf(val - bf2f(hb));
        }
}

// ---------------------------------------------------------------------------
extern "C" void kernel_launch(void* const* d_in, const int* in_sizes, int n_in,
                              void* d_out, int out_size, void* d_ws, size_t ws_size,
                              hipStream_t stream)
{
    const float* X  = (const float*)d_in[0];
    const float* Wq = (const float*)d_in[1];
    const float* Wk = (const float*)d_in[2];
    const float* Wv = (const float*)d_in[3];
    const float* Wo = (const float*)d_in[4];
    float* out = (float*)d_out;

    char* p = (char*)d_ws;
    float* q32 = (float*)p;                p += (size_t)NTOK*HID*4;
    u16* kh  = (u16*)p;                    p += (size_t)NTOK*HID*2;
    u16* km  = (u16*)p;                    p += (size_t)NTOK*HID*2;
    u16* vth = (u16*)p;                    p += (size_t)NTOK*HID*2;
    u16* Xh  = (u16*)p;                    p += (size_t)NTOK*HID*2;   // aoh alias
    u16* Xm  = (u16*)p;                    p += (size_t)NTOK*HID*2;   // aom alias
    u16* Xl  = (u16*)p;                    p += (size_t)NTOK*HID*2;
    u16* Wq3 = (u16*)p;                    p += (size_t)HID*HID*2*3;
    u16* Wk3 = (u16*)p;                    p += (size_t)HID*HID*2*3;
    u16* Wv3 = (u16*)p;                    p += (size_t)HID*HID*2*3;
    u16* Wo2 = (u16*)p;                    p += (size_t)HID*HID*2*2;
    float* partial = (float*)p;            p += (size_t)BATCH*NH*NB*2*64*4;
    float* reps    = (float*)p;            p += (size_t)BATCH*NH*NB*DH*4;
    unsigned* selm = (unsigned*)p;         p += (size_t)BATCH*NH*SEQN*4;
    float2* tab    = (float2*)p;           p += (size_t)SEQN*32*8;
    u16* aoh = Xh;
    u16* aom = Xm;

    const int NX = NTOK*HID;
    const int NW = HID*HID;

    rope_tab_k<<<dim3((SEQN*32+255)/256), 256, 0, stream>>>(tab);
    split3_k<<<dim3((NX+255)/256), 256, 0, stream>>>(X, NX, Xh, Xm, Xl);
    wsplit_k<<<dim3(NW/256, 4), 256, 0, stream>>>(Wq, Wk, Wv, Wo,
                                                  Wq3, Wk3, Wv3, Wo2);

    qkv_fused_gemm_k<<<dim3(576), 256, 0, stream>>>(
        Xh, Wq3, Wk3, Wv3, tab, q32, kh, km, vth, partial);

    reps_reduce_k<<<dim3(BATCH*NH*NB), 64, 0, stream>>>(partial, reps);
    select_topk_k<<<dim3(SEQN/128, BATCH*NH), 128, 0, stream>>>(q32, reps, selm);

    moba_attn_k<<<dim3(BATCH*NH*(SEQN/64)), 256, 0, stream>>>(
        q32, kh, km, vth, selm, aoh, aom);

    out_gemm_mfma_k<<<dim3(192), 256, 0, stream>>>(aoh, Wo2, out);
}

// Round 7
// 290.661 us; speedup vs baseline: 4.8825x; 1.0947x over previous
//
#include <hip/hip_runtime.h>
#include <math.h>

// MoBA attention, round 6: f16 2-way splits everywhere (3-product = fp32-grade),
// lo-planes stored prescaled x2048 (subnormal-safe), accumulate-lo-then-scale
// single-accumulator GEMM trick. Attention: chunk list in LDS (no scratch),
// single-plane f16 P, V single-buffered, 49KB LDS -> 3 wgs/CU.

#define HID   768
#define NH    12
#define DH    64
#define SEQN  2048
#define BATCH 2
#define NTOK  (BATCH*SEQN)   // 4096
#define NB    8
#define BLKSZ 256
#define NEG_INF (-__builtin_huge_valf())
#define POS_INF (__builtin_huge_valf())
#define LO_SCALE 2048.0f
#define LO_INV   (1.0f/2048.0f)
#define EXP2C    0.18033688f   // 0.125 * log2(e)

typedef unsigned short u16;
typedef _Float16 v8hf __attribute__((ext_vector_type(8)));
typedef float    v4f  __attribute__((ext_vector_type(4)));

__device__ __forceinline__ u16 f2h(float x) {
    _Float16 h = (_Float16)x;
    return __builtin_bit_cast(u16, h);
}
__device__ __forceinline__ float h2f(u16 u) {
    return (float)__builtin_bit_cast(_Float16, u);
}
__device__ __forceinline__ v8hf ldhf8(const u16* p) {
    return *reinterpret_cast<const v8hf*>(p);
}
__device__ __forceinline__ void g2lds16(const u16* g, u16* l) {
    __builtin_amdgcn_global_load_lds(
        (const __attribute__((address_space(1))) void*)g,
        (__attribute__((address_space(3))) void*)l, 16, 0, 0);
}
#define MFMA16(a, b, c) __builtin_amdgcn_mfma_f32_16x16x32_f16(a, b, c, 0, 0, 0)

// ---------------------------------------------------------------------------
__global__ __launch_bounds__(256)
void rope_tab_k(float2* __restrict__ tab)
{
    int i = blockIdx.x * 256 + threadIdx.x;
    if (i >= SEQN * 32) return;
    int s = i >> 5, f = i & 31;
    double y  = exp((double)f * (log(10000.0) / 32.0));
    float  yf = (float)y;
    float  invf = 1.0f / yf;
    float  ang  = (float)s * invf;
    tab[i] = make_float2((float)sin((double)ang), (float)cos((double)ang));
}

// ---------------------------------------------------------------------------
// fp32 -> f16 2-way split, lo plane prescaled x2048.
__global__ __launch_bounds__(256)
void xsplit_k(const float* __restrict__ src, int n,
              u16* __restrict__ oh, u16* __restrict__ ol)
{
    int i = blockIdx.x * 256 + threadIdx.x;
    if (i >= n) return;
    float x = src[i];
    u16 h = f2h(x);
    oh[i] = h;
    ol[i] = f2h((x - h2f(h)) * LO_SCALE);
}

__global__ __launch_bounds__(256)
void wsplit_k(const float* __restrict__ Wq, const float* __restrict__ Wk,
              const float* __restrict__ Wv, const float* __restrict__ Wo,
              u16* __restrict__ Wq2, u16* __restrict__ Wk2,
              u16* __restrict__ Wv2, u16* __restrict__ Wo2)
{
    const int NW = HID * HID;
    const int z = blockIdx.y;
    const int i = blockIdx.x * 256 + threadIdx.x;
    const float* src = (z == 0) ? Wq : (z == 1) ? Wk : (z == 2) ? Wv : Wo;
    u16* dst = (z == 0) ? Wq2 : (z == 1) ? Wk2 : (z == 2) ? Wv2 : Wo2;
    float x = src[i];
    u16 h = f2h(x);
    dst[i] = h;
    dst[i + NW] = f2h((x - h2f(h)) * LO_SCALE);
}

// ---------------------------------------------------------------------------
// 128x128 LDS-staged mainloop, f16 3-product: acc = (Al*Bh + Ah*Bl)/2048 + Ah*Bh.
__device__ __forceinline__
void gemm_mainloop(const u16* __restrict__ Ah, const u16* __restrict__ Al,
                   const u16* __restrict__ Bh, const u16* __restrict__ Bl,
                   int m0, int nb0, u16* As, u16* Bs, v4f acc[4][4])
{
    const int tid  = threadIdx.x;
    const int wave = tid >> 6, lane = tid & 63;
    const int col  = lane & 15, quad = lane >> 4;
    const int wr   = wave >> 1, wc = wave & 1;

    int ld_row[4], ld_gl[4];
    #pragma unroll
    for (int r = 0; r < 4; r++) {
        int g = r * 256 + tid;
        ld_row[r] = g >> 3;
        ld_gl[r]  = (g & 7) ^ (ld_row[r] & 7);
    }

    #pragma unroll
    for (int c = 0; c < 3; c++) {
        const u16* Ap = (c == 0) ? Al : Ah;
        const u16* Bp = (c == 1) ? Bl : Bh;
        for (int itc = 0; itc < HID / 64; itc++) {
            const int k0 = itc * 64;
            __syncthreads();
            #pragma unroll
            for (int r = 0; r < 4; r++) {
                g2lds16(Ap + (size_t)(m0 + ld_row[r]) * HID + k0 + ld_gl[r] * 8,
                        &As[(r * 256 + wave * 64) * 8]);
                g2lds16(Bp + (size_t)(nb0 + ld_row[r]) * HID + k0 + ld_gl[r] * 8,
                        &Bs[(r * 256 + wave * 64) * 8]);
            }
            __syncthreads();
            #pragma unroll
            for (int ks = 0; ks < 2; ks++) {
                v8hf af[4], bf_[4];
                #pragma unroll
                for (int mt = 0; mt < 4; mt++) {
                    const int row = wr * 64 + mt * 16 + col;
                    const int gph = (ks * 4 + quad) ^ (row & 7);
                    af[mt] = ldhf8(&As[row * 64 + gph * 8]);
                }
                #pragma unroll
                for (int nt = 0; nt < 4; nt++) {
                    const int row = wc * 64 + nt * 16 + col;
                    const int gph = (ks * 4 + quad) ^ (row & 7);
                    bf_[nt] = ldhf8(&Bs[row * 64 + gph * 8]);
                }
                #pragma unroll
                for (int mt = 0; mt < 4; mt++)
                    #pragma unroll
                    for (int nt = 0; nt < 4; nt++)
                        acc[mt][nt] = MFMA16(af[mt], bf_[nt], acc[mt][nt]);
            }
        }
        if (c == 1) {   // fold the x2048 lo-plane scaling back
            #pragma unroll
            for (int mt = 0; mt < 4; mt++)
                #pragma unroll
                for (int nt = 0; nt < 4; nt++)
                    #pragma unroll
                    for (int r = 0; r < 4; r++)
                        acc[mt][nt][r] *= LO_INV;
        }
    }
    __syncthreads();
}

// ---------------------------------------------------------------------------
// Fused QKV projection (f16 3-product) + RoPE epilogue.
// grid = 576: 18 n-tiles (Q 0-5, K 6-11, V 12-17) x 32 m-tiles.
__global__ __launch_bounds__(256)
void qkv_fused_gemm_k(const u16* __restrict__ Xh, const u16* __restrict__ Xl,
                      const u16* __restrict__ Wq2, const u16* __restrict__ Wk2,
                      const u16* __restrict__ Wv2, const float2* __restrict__ tab,
                      float* __restrict__ q32,
                      u16* __restrict__ kh16, u16* __restrict__ kl16,
                      u16* __restrict__ vth, float* __restrict__ partial)
{
    __shared__ u16 As[128 * 64];
    __shared__ u16 Bs[128 * 64];
    __shared__ float psum[2][2][64];

    const int NW = HID * HID;
    const int id    = blockIdx.x;
    const int xcd   = id & 7, loc = id >> 3;
    const int mtile = xcd * 4 + (loc & 3);
    const int ntile = loc >> 2;
    const int m0 = mtile * 128;
    const int n0 = ntile * 128;
    const int mat = n0 / HID;
    const int nb0 = n0 - mat * HID;
    const u16* Bh = (mat == 0) ? Wq2 : (mat == 1) ? Wk2 : Wv2;

    v4f acc[4][4] = {};
    gemm_mainloop(Xh, Xl, Bh, Bh + NW, m0, nb0, As, Bs, acc);

    const int tid  = threadIdx.x;
    const int wave = tid >> 6, lane = tid & 63;
    const int col  = lane & 15, quad = lane >> 4;
    const int wr   = wave >> 1, wc = wave & 1;
    const int b    = m0 >> 11;
    const int h    = (nb0 + wc * 64) >> 6;
    const size_t bh = (size_t)b * NH + h;

    if (mat == 2) {                       // V: transposed f16 store
        #pragma unroll
        for (int nt = 0; nt < 4; nt++) {
            const int d = nt * 16 + col;
            #pragma unroll
            for (int mt = 0; mt < 4; mt++) {
                const int m = m0 + wr * 64 + mt * 16 + quad * 4;
                const int s = m & (SEQN - 1);
                ushort4 pk = make_ushort4(f2h(acc[mt][nt][0]), f2h(acc[mt][nt][1]),
                                          f2h(acc[mt][nt][2]), f2h(acc[mt][nt][3]));
                *(ushort4*)&vth[(bh * DH + d) * SEQN + s] = pk;
            }
        }
        return;
    }

    // Q/K: RoPE (partner dim d^32 = acc[mt][nt^2], same lane)
    float vsum[4] = {0.f, 0.f, 0.f, 0.f};
    #pragma unroll
    for (int mt = 0; mt < 4; mt++) {
        #pragma unroll
        for (int nt = 0; nt < 4; nt++) {
            const int d = nt * 16 + col;
            #pragma unroll
            for (int r = 0; r < 4; r++) {
                const int m = m0 + wr * 64 + mt * 16 + quad * 4 + r;
                const int s = m & (SEQN - 1);
                const float part = acc[mt][nt ^ 2][r];
                const float2 sc = tab[(s << 5) + (d & 31)];
                const float val = (d < 32) ? acc[mt][nt][r] * sc.y - part * sc.x
                                           : acc[mt][nt][r] * sc.y + part * sc.x;
                const size_t idx = (bh * SEQN + s) * DH + d;
                if (mat == 0) {
                    q32[idx] = val;
                } else {
                    u16 hb = f2h(val);
                    kh16[idx] = hb;
                    kl16[idx] = f2h((val - h2f(hb)) * LO_SCALE);
                    vsum[nt] += val;
                }
            }
        }
    }
    if (mat == 1) {
        #pragma unroll
        for (int nt = 0; nt < 4; nt++) {
            float v = vsum[nt];
            v += __shfl_xor(v, 16);
            v += __shfl_xor(v, 32);
            if (quad == 0) psum[wr][wc][nt * 16 + col] = v;
        }
        __syncthreads();
        if (tid < 128) {
            const int wc2 = tid >> 6, d = tid & 63;
            const float s2 = psum[0][wc2][d] + psum[1][wc2][d];
            const int h2 = (nb0 + wc2 * 64) >> 6;
            const int nblk = (m0 & (SEQN - 1)) >> 8;
            const int half = (m0 >> 7) & 1;
            partial[((((size_t)b * NH + h2) * NB + nblk) * 2 + half) * 64 + d] = s2;
        }
    }
}

// ---------------------------------------------------------------------------
__global__ __launch_bounds__(256)
void out_gemm_mfma_k(const u16* __restrict__ Ah, const u16* __restrict__ Al,
                     const u16* __restrict__ Wo2, float* __restrict__ C)
{
    __shared__ u16 As[128 * 64];
    __shared__ u16 Bs[128 * 64];

    const int NW = HID * HID;
    const int id    = blockIdx.x;
    const int xcd   = id & 7, loc = id >> 3;
    const int mtile = xcd * 4 + (loc & 3);
    const int ntile = loc >> 2;
    const int m0 = mtile * 128;
    const int n0 = ntile * 128;

    v4f acc[4][4] = {};
    gemm_mainloop(Ah, Al, Wo2, Wo2 + NW, m0, n0, As, Bs, acc);

    const int tid  = threadIdx.x;
    const int wave = tid >> 6, lane = tid & 63;
    const int col  = lane & 15, quad = lane >> 4;
    const int wr   = wave >> 1, wc = wave & 1;

    #pragma unroll
    for (int mt = 0; mt < 4; mt++)
        #pragma unroll
        for (int nt = 0; nt < 4; nt++)
            #pragma unroll
            for (int r = 0; r < 4; r++) {
                const int m = m0 + wr * 64 + mt * 16 + quad * 4 + r;
                C[(size_t)m * HID + n0 + wc * 64 + nt * 16 + col] = acc[mt][nt][r];
            }
}

// ---------------------------------------------------------------------------
__global__ __launch_bounds__(64)
void reps_reduce_k(const float* __restrict__ partial, float* __restrict__ reps)
{
    const int bhn = blockIdx.x;
    const int d = threadIdx.x;
    const float* p = &partial[(size_t)bhn * 128 + d];
    double s = (double)p[0] + (double)p[64];
    reps[(size_t)bhn * 64 + d] = (float)(s * (1.0 / 256.0));
}

// ---------------------------------------------------------------------------
__global__ __launch_bounds__(128)
void select_topk_k(const float* __restrict__ qg, const float* __restrict__ reps,
                   unsigned* __restrict__ selm)
{
    __shared__ float rs[NB][DH];
    const int bh = blockIdx.y;
    const int tid = threadIdx.x;
    for (int idx = tid; idx < NB * DH; idx += 128)
        rs[idx >> 6][idx & 63] = reps[(size_t)bh * NB * DH + idx];
    __syncthreads();

    const int qq = blockIdx.x * 128 + tid;
    const float* qv = &qg[((size_t)bh * SEQN + qq) * DH];
    float qr[DH];
    #pragma unroll
    for (int c = 0; c < 16; c++) {
        float4 t = *(const float4*)&qv[c * 4];
        qr[c*4+0]=t.x; qr[c*4+1]=t.y; qr[c*4+2]=t.z; qr[c*4+3]=t.w;
    }
    const int cur = qq >> 8;
    double sc[NB];
    #pragma unroll
    for (int n = 0; n < NB; n++) {
        double ssum = 0.0;
        for (int d = 0; d < DH; d++) ssum += (double)qr[d] * (double)rs[n][d];
        sc[n] = ssum * 0.125;
    }
    for (int n = cur + 1; n < NB; n++) sc[n] = -1e300;
    sc[cur] = 1e300;
    unsigned mask = 0;
    for (int p = 0; p < 3; p++) {
        int bi = -1; double bv = 0.0;
        for (int n = 0; n < NB; n++) {
            if ((mask >> n) & 1) continue;
            if (bi < 0 || sc[n] > bv) { bi = n; bv = sc[n]; }
        }
        mask |= 1u << bi;
    }
    selm[(size_t)bh * SEQN + qq] = mask;
}

// ---------------------------------------------------------------------------
// f16 MFMA flash attention. wg = 256 thr = one 64-query tile; K hi/lo dbuf
// LDS staging, V single-buffered (2nd barrier), chunk list in LDS, P single
// f16 plane (XOR-swizzled), softmax scale folded into exp2 constant.
__global__ __launch_bounds__(256, 3)
void moba_attn_k(const float* __restrict__ q32,
                 const u16* __restrict__ kh16, const u16* __restrict__ kl16,
                 const u16* __restrict__ vth, const unsigned* __restrict__ selm,
                 u16* __restrict__ aoh, u16* __restrict__ aol)
{
    __shared__ u16 kbuf[2][2][64 * 64];   // 32 KB: [buf][hi/lo]
    __shared__ u16 vbuf[64 * 64];         // 8 KB, single-buffered
    __shared__ u16 plds[4][16][64];       // 8 KB: per-wave P (f16, swizzled)
    __shared__ unsigned char clist_n[36], clist_c[36];
    __shared__ int s_T;
    __shared__ unsigned s_uni;

    const int id  = blockIdx.x;                 // 768
    const int xcd = id & 7, loc = id >> 3;      // 96 per XCD
    const int bh  = xcd * 3 + (loc >> 5);       // 3 bh per XCD
    const int q0  = (loc & 31) * 64;
    const int cur = q0 >> 8;
    const int tid = threadIdx.x;
    const int wave = tid >> 6, lane = tid & 63;
    const int col = lane & 15, quad = lane >> 4;
    const int qw0 = q0 + wave * 16;
    const int qpos = qw0 + col;
    const size_t bhS = (size_t)bh * SEQN;

    if (tid == 0) s_uni = 0;
    __syncthreads();
    const unsigned mymask = selm[bhS + qw0 + col];
    unsigned uw = mymask;
    #pragma unroll
    for (int off = 1; off < 16; off <<= 1) uw |= __shfl_xor(uw, off);
    if (lane == 0) atomicOr(&s_uni, uw);

    // Q fragments: f16 2-split, lo prescaled x2048 (subnormal-safe)
    v8hf qh[2], ql[2];
    #pragma unroll
    for (int ks = 0; ks < 2; ks++) {
        const float* qp = &q32[(bhS + qw0 + col) * DH + ks * 32 + quad * 8];
        float4 f0 = *(const float4*)qp;
        float4 f1 = *(const float4*)(qp + 4);
        float qf[8] = {f0.x, f0.y, f0.z, f0.w, f1.x, f1.y, f1.z, f1.w};
        union { u16 u[8]; v8hf h; } uh, ul;
        #pragma unroll
        for (int j = 0; j < 8; j++) {
            u16 hb = f2h(qf[j]);
            uh.u[j] = hb;
            ul.u[j] = f2h((qf[j] - h2f(hb)) * LO_SCALE);
        }
        qh[ks] = uh.h; ql[ks] = ul.h;
    }
    __syncthreads();

    // chunk list (wg-uniform) in LDS
    if (tid == 0) {
        const unsigned u = s_uni;
        int T = 0;
        for (int n = 0; n < NB; n++) {
            if (!((u >> n) & 1)) continue;
            const int cm = (n == cur) ? ((q0 + 63 - n * BLKSZ) >> 6) : 3;
            for (int c2 = 0; c2 <= cm; c2++) {
                clist_n[T] = (unsigned char)n;
                clist_c[T] = (unsigned char)c2;
                T++;
            }
        }
        s_T = T;
    }
    __syncthreads();
    const int T = s_T;

    // staging helpers (granule g = tid covers rows 0-31; +256 rows 32-63)
    const int sg_row0 = tid >> 3;
    const int sg_gl0  = (tid & 7) ^ (sg_row0 & 7);
    const int sg_row1 = (256 + tid) >> 3;
    const int sg_gl1  = ((256 + tid) & 7) ^ (sg_row1 & 7);
    auto stageK = [&](int t) {
        const int kb = (int)clist_n[t] * BLKSZ + (int)clist_c[t] * 64;
        u16* k0 = (u16*)kbuf[t & 1][0];
        u16* k1 = (u16*)kbuf[t & 1][1];
        const size_t ks0 = (bhS + kb + sg_row0) * DH + sg_gl0 * 8;
        const size_t ks1 = (bhS + kb + sg_row1) * DH + sg_gl1 * 8;
        g2lds16(kh16 + ks0, k0 + (wave * 64) * 8);
        g2lds16(kh16 + ks1, k0 + (256 + wave * 64) * 8);
        g2lds16(kl16 + ks0, k1 + (wave * 64) * 8);
        g2lds16(kl16 + ks1, k1 + (256 + wave * 64) * 8);
    };
    auto stageV = [&](int t) {
        const int kb = (int)clist_n[t] * BLKSZ + (int)clist_c[t] * 64;
        u16* vb = (u16*)vbuf;
        const size_t vs0 = ((size_t)bh * DH + sg_row0) * SEQN + kb + sg_gl0 * 8;
        const size_t vs1 = ((size_t)bh * DH + sg_row1) * SEQN + kb + sg_gl1 * 8;
        g2lds16(vth + vs0, vb + (wave * 64) * 8);
        g2lds16(vth + vs1, vb + (256 + wave * 64) * 8);
    };

    const v4f zero4 = {0.f, 0.f, 0.f, 0.f};
    v4f oacc[4] = {zero4, zero4, zero4, zero4};
    float m_i = NEG_INF, l_i = 0.f;
    const int psw = (col & 7) << 1;            // P swizzle (even XOR)

    stageK(0);
    for (int t = 0; t < T; t++) {
        __syncthreads();                       // barrier A: K(t) ready, vbuf free
        if (t + 1 < T) stageK(t + 1);
        stageV(t);

        const int n  = (int)clist_n[t];
        const int kb = n * BLKSZ + (int)clist_c[t] * 64;
        const bool iscur = (n == cur);
        const float selinf = ((mymask >> n) & 1) ? 0.f : POS_INF;
        const bool need_mask = iscur && (kb + 63 > qw0);
        const u16* k0 = (const u16*)kbuf[t & 1][0];
        const u16* k1 = (const u16*)kbuf[t & 1][1];

        // ---- S^T[64k x 16q]: (Kl*Qh + Kh*Ql)/2048 + Kh*Qh (raw scores)
        v4f sf[4];
        #pragma unroll
        for (int mt = 0; mt < 4; mt++) {
            const int row = mt * 16 + col;
            const int r7 = row & 7;
            v8hf kh0 = ldhf8(&k0[(row * 8 + (quad ^ r7)) * 8]);
            v8hf kh1 = ldhf8(&k0[(row * 8 + ((4 + quad) ^ r7)) * 8]);
            v8hf kl0 = ldhf8(&k1[(row * 8 + (quad ^ r7)) * 8]);
            v8hf kl1 = ldhf8(&k1[(row * 8 + ((4 + quad) ^ r7)) * 8]);
            v4f c = zero4;
            c = MFMA16(kl0, qh[0], c);
            c = MFMA16(kl1, qh[1], c);
            c = MFMA16(kh0, ql[0], c);
            c = MFMA16(kh1, ql[1], c);
            #pragma unroll
            for (int r = 0; r < 4; r++) c[r] *= LO_INV;
            c = MFMA16(kh0, qh[0], c);
            c = MFMA16(kh1, qh[1], c);
            sf[mt] = c;
        }

        if (need_mask) {
            #pragma unroll
            for (int mt = 0; mt < 4; mt++)
                #pragma unroll
                for (int r = 0; r < 4; r++) {
                    const int kidx = kb + mt * 16 + quad * 4 + r;
                    sf[mt][r] = (kidx <= qpos) ? sf[mt][r] : NEG_INF;
                }
        }

        // ---- row max (raw domain), softmax via exp2 with folded 0.125 scale
        float rm = NEG_INF;
        #pragma unroll
        for (int mt = 0; mt < 4; mt++)
            #pragma unroll
            for (int r = 0; r < 4; r++) rm = fmaxf(rm, sf[mt][r]);
        rm = fmaxf(rm, __shfl_xor(rm, 16));
        rm = fmaxf(rm, __shfl_xor(rm, 32));
        rm = rm - selinf;                      // unselected lanes -> -inf
        const float mnew  = fmaxf(m_i, rm);
        const float alpha = (m_i == NEG_INF) ? 0.f : exp2f((m_i - mnew) * EXP2C);
        const float biasC = ((mnew == NEG_INF) ? 0.f : mnew * EXP2C) + selinf;

        float lsum = 0.f;
        #pragma unroll
        for (int mt = 0; mt < 4; mt++) {
            ushort4 hv;
            #pragma unroll
            for (int r = 0; r < 4; r++) {
                float p = exp2f(fmaf(sf[mt][r], EXP2C, -biasC));
                lsum += p;
                u16 hu = f2h(p);
                if (r == 0) hv.x = hu;
                else if (r == 1) hv.y = hu;
                else if (r == 2) hv.z = hu;
                else hv.w = hu;
            }
            *(ushort4*)&plds[wave][col][((mt * 4 + quad) ^ psw) * 4] = hv;
        }
        lsum += __shfl_xor(lsum, 16);
        lsum += __shfl_xor(lsum, 32);
        l_i = l_i * alpha + lsum;
        m_i = mnew;

        float ar[4];
        #pragma unroll
        for (int r = 0; r < 4; r++) ar[r] = __shfl(alpha, quad * 4 + r, 16);
        #pragma unroll
        for (int nt = 0; nt < 4; nt++)
            #pragma unroll
            for (int r = 0; r < 4; r++) oacc[nt][r] *= ar[r];

        __syncthreads();                       // barrier B: V(t) staged, P visible

        // ---- O += P * V  (P single f16; V f16 from LDS)
        #pragma unroll
        for (int ks2 = 0; ks2 < 2; ks2++) {
            v8hf ph = ldhf8(&plds[wave][col][((ks2 * 8 + quad * 2) ^ psw) * 4]);
            #pragma unroll
            for (int nt = 0; nt < 4; nt++) {
                const int row = nt * 16 + col;
                const int g = (ks2 * 4 + quad) ^ (row & 7);
                v8hf vh = ldhf8(&vbuf[(row * 8 + g) * 8]);
                oacc[nt] = MFMA16(ph, vh, oacc[nt]);
            }
        }
    }

    // ---- epilogue: normalize, f16 2-split store of attn-out
    const int b = bh / NH, h = bh % NH;
    const float invl = 1.f / l_i;
    float ir[4];
    #pragma unroll
    for (int r = 0; r < 4; r++) ir[r] = __shfl(invl, quad * 4 + r, 16);
    #pragma unroll
    for (int nt = 0; nt < 4; nt++)
        #pragma unroll
        for (int r = 0; r < 4; r++) {
            const int qi = qw0 + quad * 4 + r;
            const size_t idx = ((size_t)b * SEQN + qi) * HID + h * DH + nt * 16 + col;
            float val = oacc[nt][r] * ir[r];
            u16 hb = f2h(val);
            aoh[idx] = hb;
            aol[idx] = f2h((val - h2f(hb)) * LO_SCALE);
        }
}

// ---------------------------------------------------------------------------
extern "C" void kernel_launch(void* const* d_in, const int* in_sizes, int n_in,
                              void* d_out, int out_size, void* d_ws, size_t ws_size,
                              hipStream_t stream)
{
    const float* X  = (const float*)d_in[0];
    const float* Wq = (const float*)d_in[1];
    const float* Wk = (const float*)d_in[2];
    const float* Wv = (const float*)d_in[3];
    const float* Wo = (const float*)d_in[4];
    float* out = (float*)d_out;

    char* p = (char*)d_ws;
    float* q32 = (float*)p;                p += (size_t)NTOK*HID*4;
    u16* kh16 = (u16*)p;                   p += (size_t)NTOK*HID*2;
    u16* kl16 = (u16*)p;                   p += (size_t)NTOK*HID*2;
    u16* vth  = (u16*)p;                   p += (size_t)NTOK*HID*2;
    u16* Xh   = (u16*)p;                   p += (size_t)NTOK*HID*2;   // aoh alias
    u16* Xl   = (u16*)p;                   p += (size_t)NTOK*HID*2;   // aol alias
    u16* Wq2  = (u16*)p;                   p += (size_t)HID*HID*2*2;
    u16* Wk2  = (u16*)p;                   p += (size_t)HID*HID*2*2;
    u16* Wv2  = (u16*)p;                   p += (size_t)HID*HID*2*2;
    u16* Wo2  = (u16*)p;                   p += (size_t)HID*HID*2*2;
    float* partial = (float*)p;            p += (size_t)BATCH*NH*NB*2*64*4;
    float* reps    = (float*)p;            p += (size_t)BATCH*NH*NB*DH*4;
    unsigned* selm = (unsigned*)p;         p += (size_t)BATCH*NH*SEQN*4;
    float2* tab    = (float2*)p;           p += (size_t)SEQN*32*8;
    u16* aoh = Xh;
    u16* aol = Xl;

    const int NX = NTOK*HID;
    const int NW = HID*HID;

    rope_tab_k<<<dim3((SEQN*32+255)/256), 256, 0, stream>>>(tab);
    xsplit_k<<<dim3((NX+255)/256), 256, 0, stream>>>(X, NX, Xh, Xl);
    wsplit_k<<<dim3(NW/256, 4), 256, 0, stream>>>(Wq, Wk, Wv, Wo,
                                                  Wq2, Wk2, Wv2, Wo2);

    qkv_fused_gemm_k<<<dim3(576), 256, 0, stream>>>(
        Xh, Xl, Wq2, Wk2, Wv2, tab, q32, kh16, kl16, vth, partial);

    reps_reduce_k<<<dim3(BATCH*NH*NB), 64, 0, stream>>>(partial, reps);
    select_topk_k<<<dim3(SEQN/128, BATCH*NH), 128, 0, stream>>>(q32, reps, selm);

    moba_attn_k<<<dim3(BATCH*NH*(SEQN/64)), 256, 0, stream>>>(
        q32, kh16, kl16, vth, selm, aoh, aol);

    out_gemm_mfma_k<<<dim3(192), 256, 0, stream>>>(aoh, Xl, Wo2, out);
}